// Round 2
// 1073.304 us; speedup vs baseline: 1.1889x; 1.1889x over previous
//
#include <hip/hip_runtime.h>
#include <hip/hip_bf16.h>

typedef __hip_bfloat16 bf16;
typedef unsigned short u16;
typedef u16 u16x8 __attribute__((ext_vector_type(8)));
typedef __bf16 bf16x8 __attribute__((ext_vector_type(8)));
typedef float f32x4 __attribute__((ext_vector_type(4)));

__device__ __forceinline__ float tof(float x) { return x; }
__device__ __forceinline__ float tof(bf16 x) { return __bfloat162float(x); }
__device__ __forceinline__ bf16 tobf(float x) { return __float2bfloat16(x); }

// round-to-nearest-even f32 -> bf16 bits (matches __float2bfloat16 for normals)
__device__ __forceinline__ u16 f2bf(float x) {
    unsigned u = __builtin_bit_cast(unsigned, x);
    u += 0x7fffu + ((u >> 16) & 1u);
    return (u16)(u >> 16);
}
__device__ __forceinline__ float bf2f(u16 h) {
    return __builtin_bit_cast(float, (unsigned)h << 16);
}

// ---- W pre-transpose + split: W[K][N] f32 -> Wt_hi/Wt_lo[N][K] bf16 ------
__global__ void tsplit_k(const float* __restrict__ W, int K, int N,
                         u16* __restrict__ hi, u16* __restrict__ lo)
{
    int i = blockIdx.x * blockDim.x + threadIdx.x;
    if (i >= K * N) return;
    int k = i / N, n = i - k * N;
    float v = W[i];
    u16 h = f2bf(v);
    hi[(long)n * K + k] = h;
    lo[(long)n * K + k] = f2bf(v - bf2f(h));
}

// ---- split-precision MFMA GEMM: C[M,Ntot](bf16) = A[M,K] @ B[K,Ntot] ----
// B supplied pre-transposed + hi/lo split: Bhi/Blo[Ntot][K] bf16.
// SPLIT_A:  A is f32, split on the fly (3 MFMAs: ah*bh + al*bh + ah*bl)
// !SPLIT_A: A is bf16 exact              (2 MFMAs: a*bh + a*bl)
// Tile 128x128, BK=64, 256 threads = 4 waves (2x2), 64x64 per wave.
// LDS layout: row-major [128][64] bf16 with 16B-chunk XOR swizzle
// (chunk ^ (row&7)) to kill the stride-128B bank conflict (Guideline 4).
template <bool SPLIT_A>
__global__ __launch_bounds__(256) void gemm_mfma(
    const void* __restrict__ Avoid, const u16* __restrict__ Bhi,
    const u16* __restrict__ Blo, u16* __restrict__ C,
    int M, int Ntot, int K)
{
    __shared__ u16 AsHi[128 * 64];
    __shared__ u16 AsLo[SPLIT_A ? 128 * 64 : 8];
    __shared__ u16 BsHi[128 * 64];
    __shared__ u16 BsLo[128 * 64];
    const int t = threadIdx.x;
    const long bm = (long)blockIdx.y * 128;
    const int bn = blockIdx.x * 128;
    const int srow = t >> 1;      // staging row/col 0..127
    const int skh  = t & 1;       // staging k-half (32 elems)
    const int w  = t >> 6;
    const int wm = (w >> 1) * 64; // wave row base
    const int wn = (w & 1) * 64;  // wave col base
    const int l  = t & 63;
    const int lr = l & 15;        // fragment row/col
    const int lg = l >> 4;        // fragment k-group

    f32x4 acc[4][4];
#pragma unroll
    for (int i = 0; i < 4; ++i)
#pragma unroll
        for (int j = 0; j < 4; ++j) acc[i][j] = {0.f, 0.f, 0.f, 0.f};

    for (int k0 = 0; k0 < K; k0 += 64) {
        // ---- stage A (reg-staged; swizzled LDS writes) ----
        {
            long r = bm + srow;
            bool ok = r < M;
            if (SPLIT_A) {
                const float* A = (const float*)Avoid;
                const float4* ap = (const float4*)(A + r * K + k0 + skh * 32);
#pragma unroll
                for (int c = 0; c < 4; ++c) {
                    float va[8];
                    if (ok) {
                        float4 v0 = ap[c * 2], v1 = ap[c * 2 + 1];
                        va[0] = v0.x; va[1] = v0.y; va[2] = v0.z; va[3] = v0.w;
                        va[4] = v1.x; va[5] = v1.y; va[6] = v1.z; va[7] = v1.w;
                    } else {
#pragma unroll
                        for (int j = 0; j < 8; ++j) va[j] = 0.f;
                    }
                    u16x8 hi, lo;
#pragma unroll
                    for (int j = 0; j < 8; ++j) {
                        u16 h = f2bf(va[j]);
                        hi[j] = h;
                        lo[j] = f2bf(va[j] - bf2f(h));
                    }
                    int off = srow * 128 + ((((skh * 4 + c) ^ (srow & 7))) << 4);
                    *(u16x8*)((char*)AsHi + off) = hi;
                    *(u16x8*)((char*)AsLo + off) = lo;
                }
            } else {
                const u16* A = (const u16*)Avoid;
                const u16x8* ap = (const u16x8*)(A + r * K + k0 + skh * 32);
#pragma unroll
                for (int c = 0; c < 4; ++c) {
                    u16x8 hv = {0, 0, 0, 0, 0, 0, 0, 0};
                    if (ok) hv = ap[c];
                    int off = srow * 128 + ((((skh * 4 + c) ^ (srow & 7))) << 4);
                    *(u16x8*)((char*)AsHi + off) = hv;
                }
            }
        }
        // ---- stage B ----
        {
            const u16x8* bph = (const u16x8*)(Bhi + (long)(bn + srow) * K + k0 + skh * 32);
            const u16x8* bpl = (const u16x8*)(Blo + (long)(bn + srow) * K + k0 + skh * 32);
#pragma unroll
            for (int c = 0; c < 4; ++c) {
                int off = srow * 128 + ((((skh * 4 + c) ^ (srow & 7))) << 4);
                *(u16x8*)((char*)BsHi + off) = bph[c];
                *(u16x8*)((char*)BsLo + off) = bpl[c];
            }
        }
        __syncthreads();
        // ---- MFMA compute ----
#pragma unroll
        for (int ks = 0; ks < 2; ++ks) {
            bf16x8 bh[4], bl[4];
            const int chl = ks * 4 + lg;  // linear 16B chunk 0..7
#pragma unroll
            for (int n = 0; n < 4; ++n) {
                int col = wn + n * 16 + lr;
                int off = col * 128 + (((chl ^ (col & 7))) << 4);
                bh[n] = *(const bf16x8*)((const char*)BsHi + off);
                bl[n] = *(const bf16x8*)((const char*)BsLo + off);
            }
#pragma unroll
            for (int m = 0; m < 4; ++m) {
                int row = wm + m * 16 + lr;
                int off = row * 128 + (((chl ^ (row & 7))) << 4);
                bf16x8 ah = *(const bf16x8*)((const char*)AsHi + off);
#pragma unroll
                for (int n = 0; n < 4; ++n)
                    acc[m][n] = __builtin_amdgcn_mfma_f32_16x16x32_bf16(
                        ah, bh[n], acc[m][n], 0, 0, 0);
#pragma unroll
                for (int n = 0; n < 4; ++n)
                    acc[m][n] = __builtin_amdgcn_mfma_f32_16x16x32_bf16(
                        ah, bl[n], acc[m][n], 0, 0, 0);
                if (SPLIT_A) {
                    bf16x8 al = *(const bf16x8*)((const char*)AsLo + off);
#pragma unroll
                    for (int n = 0; n < 4; ++n)
                        acc[m][n] = __builtin_amdgcn_mfma_f32_16x16x32_bf16(
                            al, bh[n], acc[m][n], 0, 0, 0);
                }
            }
        }
        __syncthreads();
    }
    // ---- C write: D(reg i, lane l) = C[base + lg*4 + i][base + lr] ----
#pragma unroll
    for (int m = 0; m < 4; ++m) {
        long r0 = bm + wm + m * 16 + lg * 4;
#pragma unroll
        for (int i = 0; i < 4; ++i) {
            long r = r0 + i;
            if (r < M) {
#pragma unroll
                for (int n = 0; n < 4; ++n) {
                    int col = bn + wn + n * 16 + lr;
                    C[r * Ntot + col] = f2bf(acc[m][n][i]);
                }
            }
        }
    }
}

// ---- layer-1 attention logits, 4 heads of C=32: [N,4] -------------------
__global__ void alpha4_k(const bf16* __restrict__ h, const float* __restrict__ asrc,
                         const float* __restrict__ adst, float* __restrict__ out_s,
                         float* __restrict__ out_d, int N)
{
    int i = blockIdx.x * blockDim.x + threadIdx.x;
    if (i >= N * 4) return;
    int n = i >> 2, hh = i & 3;
    const bf16* row = h + (long)n * 128 + hh * 32;
    const float* av = asrc + hh * 32;
    const float* bv = adst + hh * 32;
    float s1 = 0.f, s2 = 0.f;
    for (int c = 0; c < 32; ++c) {
        float v = tof(row[c]);
        s1 += v * av[c];
        s2 += v * bv[c];
    }
    out_s[i] = s1;
    out_d[i] = s2;
}

// ---- layer-2 attention logits: one wave per (node, head), C=128 ---------
__global__ __launch_bounds__(256) void alpha2w_k(
    const bf16* __restrict__ h2, const float* __restrict__ as2,
    const float* __restrict__ ad2, float* __restrict__ out_s,
    float* __restrict__ out_d, int N)
{
    int n = blockIdx.x;
    int w = threadIdx.x >> 6;   // head
    int l = threadIdx.x & 63;
    const bf16* row = h2 + (long)n * 512 + w * 128;
    float v0 = tof(row[l]), v1 = tof(row[l + 64]);
    float s1 = v0 * as2[w * 128 + l] + v1 * as2[w * 128 + l + 64];
    float s2 = v0 * ad2[w * 128 + l] + v1 * ad2[w * 128 + l + 64];
#pragma unroll
    for (int off = 32; off; off >>= 1) {
        s1 += __shfl_down(s1, off);
        s2 += __shfl_down(s2, off);
    }
    if (l == 0) { out_s[n * 4 + w] = s1; out_d[n * 4 + w] = s2; }
}

// ---- CSR build ----------------------------------------------------------
__global__ void init_cnt_k(int* __restrict__ cnt, int N)
{
    int i = blockIdx.x * blockDim.x + threadIdx.x;
    if (i < N) cnt[i] = 1;  // self-loop
}

__global__ void hist_k(const int* __restrict__ dst, int E, int* __restrict__ cnt)
{
    int e = blockIdx.x * blockDim.x + threadIdx.x;
    if (e < E) atomicAdd(&cnt[dst[e]], 1);
}

__global__ __launch_bounds__(256) void scan_blk_k(const int* __restrict__ cnt,
                                                  int* __restrict__ row_ptr,
                                                  int* __restrict__ bsum, int N)
{
    __shared__ int s[256];
    int t = threadIdx.x;
    int i = blockIdx.x * 256 + t;
    int v = (i < N) ? cnt[i] : 0;
    s[t] = v;
    __syncthreads();
    for (int off = 1; off < 256; off <<= 1) {
        int x = (t >= off) ? s[t - off] : 0;
        __syncthreads();
        s[t] += x;
        __syncthreads();
    }
    if (i < N) row_ptr[i] = s[t] - v;  // exclusive
    if (t == 255) bsum[blockIdx.x] = s[255];
}

__global__ __launch_bounds__(512) void scan_top_k(const int* __restrict__ bsum,
                                                  int* __restrict__ bofs, int B)
{
    __shared__ int s[512];
    int t = threadIdx.x;
    int v = (t < B) ? bsum[t] : 0;
    s[t] = v;
    __syncthreads();
    for (int off = 1; off < 512; off <<= 1) {
        int x = (t >= off) ? s[t - off] : 0;
        __syncthreads();
        s[t] += x;
        __syncthreads();
    }
    bofs[t] = s[t] - v;  // exclusive
}

__global__ void add_off_k(int* __restrict__ row_ptr, const int* __restrict__ bofs,
                          int* __restrict__ wofs, int N, int Etot)
{
    int i = blockIdx.x * blockDim.x + threadIdx.x;
    if (i == 0) row_ptr[N] = Etot;
    if (i >= N) return;
    int r = row_ptr[i] + bofs[i >> 8];
    row_ptr[i] = r;
    wofs[i] = r;
}

__global__ void scatter_k(const int* __restrict__ dst, int E, int Etot,
                          int* __restrict__ wofs, int* __restrict__ eidx)
{
    int e = blockIdx.x * blockDim.x + threadIdx.x;
    if (e >= Etot) return;
    int d = (e < E) ? dst[e] : (e - E);
    int pos = atomicAdd(&wofs[d], 1);
    eidx[pos] = e;
}

// ---- layer-1: fused per-node softmax + gather-aggregate + bias + ELU ----
__global__ __launch_bounds__(128) void agg1_gather_k(
    const int* __restrict__ row_ptr, const int* __restrict__ eidx,
    const int* __restrict__ src, int E,
    const float* __restrict__ asv, const float* __restrict__ adv,
    const bf16* __restrict__ h1, const float* __restrict__ b1,
    bf16* __restrict__ out1b)
{
    int d = blockIdx.x;
    int t = threadIdx.x;
    int hh = t >> 5;
    int beg = row_ptr[d], end = row_ptr[d + 1];
    float ad_d = adv[d * 4 + hh];
    float m = -1e30f;
    for (int j = beg; j < end; ++j) {
        int e = eidx[j];
        int s = (e < E) ? src[e] : d;
        float l = asv[s * 4 + hh] + ad_d;
        l = l > 0.f ? l : 0.2f * l;
        m = fmaxf(m, l);
    }
    float den = 0.f, acc = 0.f;
    for (int j = beg; j < end; ++j) {
        int e = eidx[j];
        int s = (e < E) ? src[e] : d;
        float l = asv[s * 4 + hh] + ad_d;
        l = l > 0.f ? l : 0.2f * l;
        float w = __expf(l - m);
        den += w;
        acc += w * tof(h1[(long)s * 128 + t]);
    }
    float v = acc / (den + 1e-16f) + b1[t];
    v = v > 0.f ? v : (__expf(v) - 1.f);
    out1b[(long)d * 128 + t] = tobf(v);
}

// ---- layer-2: fused per-node 4-head softmax + gather + head-mean + bias --
__global__ __launch_bounds__(128) void agg2_gather_k(
    const int* __restrict__ row_ptr, const int* __restrict__ eidx,
    const int* __restrict__ src, int E,
    const float* __restrict__ asv, const float* __restrict__ adv,
    const bf16* __restrict__ h2, const float* __restrict__ b2,
    float* __restrict__ emb)
{
    int d = blockIdx.x;
    int c = threadIdx.x;
    int beg = row_ptr[d], end = row_ptr[d + 1];
    float ad0 = adv[d * 4 + 0], ad1 = adv[d * 4 + 1];
    float ad2_ = adv[d * 4 + 2], ad3 = adv[d * 4 + 3];
    float m0 = -1e30f, m1 = -1e30f, m2 = -1e30f, m3 = -1e30f;
    for (int j = beg; j < end; ++j) {
        int e = eidx[j];
        int s = (e < E) ? src[e] : d;
        float l0 = asv[s * 4 + 0] + ad0; l0 = l0 > 0.f ? l0 : 0.2f * l0;
        float l1 = asv[s * 4 + 1] + ad1; l1 = l1 > 0.f ? l1 : 0.2f * l1;
        float l2 = asv[s * 4 + 2] + ad2_; l2 = l2 > 0.f ? l2 : 0.2f * l2;
        float l3 = asv[s * 4 + 3] + ad3; l3 = l3 > 0.f ? l3 : 0.2f * l3;
        m0 = fmaxf(m0, l0); m1 = fmaxf(m1, l1);
        m2 = fmaxf(m2, l2); m3 = fmaxf(m3, l3);
    }
    float d0 = 0.f, d1 = 0.f, d2 = 0.f, d3 = 0.f;
    float a0 = 0.f, a1 = 0.f, a2 = 0.f, a3 = 0.f;
    for (int j = beg; j < end; ++j) {
        int e = eidx[j];
        int s = (e < E) ? src[e] : d;
        float l0 = asv[s * 4 + 0] + ad0; l0 = l0 > 0.f ? l0 : 0.2f * l0;
        float l1 = asv[s * 4 + 1] + ad1; l1 = l1 > 0.f ? l1 : 0.2f * l1;
        float l2 = asv[s * 4 + 2] + ad2_; l2 = l2 > 0.f ? l2 : 0.2f * l2;
        float l3 = asv[s * 4 + 3] + ad3; l3 = l3 > 0.f ? l3 : 0.2f * l3;
        float w0 = __expf(l0 - m0), w1 = __expf(l1 - m1);
        float w2 = __expf(l2 - m2), w3 = __expf(l3 - m3);
        d0 += w0; d1 += w1; d2 += w2; d3 += w3;
        const bf16* hrow = h2 + (long)s * 512 + c;
        a0 += w0 * tof(hrow[0]);
        a1 += w1 * tof(hrow[128]);
        a2 += w2 * tof(hrow[256]);
        a3 += w3 * tof(hrow[384]);
    }
    float v = a0 / (d0 + 1e-16f) + a1 / (d1 + 1e-16f) +
              a2 / (d2 + 1e-16f) + a3 / (d3 + 1e-16f);
    emb[(long)d * 128 + c] = 0.25f * v + b2[c];
}

// ---- final linear: out[N,64] = emb[N,128] @ W_lin + b -------------------
__global__ __launch_bounds__(256) void final_k(const float* __restrict__ emb,
                                               const float* __restrict__ W,
                                               const float* __restrict__ bias,
                                               float* __restrict__ out, int N)
{
    __shared__ float Ws[128 * 64];
    __shared__ float Es[4][132];
    const int tid = threadIdx.x;
    for (int i = tid; i < 128 * 64; i += 256) Ws[i] = W[i];
    int node0 = blockIdx.x * 4;
    for (int i = tid; i < 512; i += 256) {
        int nn = i >> 7, c = i & 127;
        int n = node0 + nn;
        Es[nn][c] = (n < N) ? emb[(long)n * 128 + c] : 0.f;
    }
    __syncthreads();
    int nn = tid >> 6, j = tid & 63;
    int n = node0 + nn;
    if (n >= N) return;
    float acc = bias[j];
#pragma unroll 8
    for (int k = 0; k < 128; ++k) acc += Es[nn][k] * Ws[k * 64 + j];
    out[(long)n * 64 + j] = acc;
}

// ---- diagnostic ---------------------------------------------------------
__global__ void diag_k(float* __restrict__ out, long n, float val)
{
    long i = (long)blockIdx.x * blockDim.x + threadIdx.x;
    if (i >= n) return;
    out[i] = val;
}

extern "C" void kernel_launch(void* const* d_in, const int* in_sizes, int n_in,
                              void* d_out, int out_size, void* d_ws, size_t ws_size,
                              hipStream_t stream)
{
    const float* x   = (const float*)d_in[0];
    const int* ei    = (const int*)d_in[1];
    const float* W1  = (const float*)d_in[2];
    const float* as1 = (const float*)d_in[3];
    const float* ad1 = (const float*)d_in[4];
    const float* b1  = (const float*)d_in[5];
    const float* W2  = (const float*)d_in[6];
    const float* as2 = (const float*)d_in[7];
    const float* ad2 = (const float*)d_in[8];
    const float* b2  = (const float*)d_in[9];
    const float* Wl  = (const float*)d_in[10];
    const float* bl  = (const float*)d_in[11];

    const int N = in_sizes[0] / 512;
    const int E = in_sizes[1] / 2;
    const int Etot = E + N;
    const int* src = ei;
    const int* dst = ei + E;

    float* outp = (float*)d_out;          // [N,64]
    float* embp = outp + (size_t)N * 64;  // [N,128] f32
    // out1b (bf16 [N,128]) parked inside the embp region (dead before agg2 writes emb)
    bf16* out1b = (bf16*)embp;

    // ---- workspace layout (~107 MB; known-safe floor from R3 diag = 119.6 MB) ----
    char* wsb = (char*)d_ws;
    bf16*  h2    = (bf16*)wsb;                              // N*512 bf16
    bf16*  h1    = (bf16*)wsb;                              // N*128 bf16 (alias)
    float* asv   = (float*)(wsb + (size_t)N * 512 * sizeof(bf16));  // N*4
    float* adv   = asv + (size_t)N * 4;                     // N*4
    int*   cnt   = (int*)(adv + (size_t)N * 4);             // N
    int*   row_ptr = cnt + N;                               // N+1
    int*   wofs  = row_ptr + (N + 1);                       // N
    int*   bsum  = wofs + N;                                // 512
    int*   bofs  = bsum + 512;                              // 512
    int*   eidx  = bofs + 512;                              // Etot
    // transposed + hi/lo-split weights (bf16), 256B-aligned
    char*  pw    = (char*)(eidx + Etot);
    pw = (char*)(((uintptr_t)pw + 255) & ~(uintptr_t)255);
    u16*   w1t_hi = (u16*)pw;                               // [128][512]
    u16*   w1t_lo = w1t_hi + 128 * 512;
    u16*   w2t_hi = w1t_lo + 128 * 512;                     // [512][128]
    u16*   w2t_lo = w2t_hi + 512 * 128;
    size_t need  = (size_t)((char*)(w2t_lo + 512 * 128) - wsb);

    dim3 blk(256);
    long n_out_total = (long)N * 192;

    if (ws_size < need) {
        float val = 100.0f + (float)(ws_size >> 20);
        diag_k<<<(int)((n_out_total + 255) / 256), blk, 0, stream>>>(outp, n_out_total, val);
        return;
    }

    const int B = (N + 255) / 256;  // scan blocks (<=512 for N<=131072)
    const int gM = (N + 127) / 128; // MFMA gemm row-blocks

    // ---- weight transpose+split (tiny, independent of everything) ----
    tsplit_k<<<(512 * 128 + 255) / 256, blk, 0, stream>>>(W1, 512, 128, w1t_hi, w1t_lo);
    tsplit_k<<<(128 * 512 + 255) / 256, blk, 0, stream>>>(W2, 128, 512, w2t_hi, w2t_lo);

    // ---- CSR build (by dst) ----
    init_cnt_k<<<B, blk, 0, stream>>>(cnt, N);
    hist_k<<<(E + 255) / 256, blk, 0, stream>>>(dst, E, cnt);
    scan_blk_k<<<B, blk, 0, stream>>>(cnt, row_ptr, bsum, N);
    scan_top_k<<<1, 512, 0, stream>>>(bsum, bofs, B);
    add_off_k<<<B, blk, 0, stream>>>(row_ptr, bofs, wofs, N, Etot);
    scatter_k<<<(Etot + 255) / 256, blk, 0, stream>>>(dst, E, Etot, wofs, eidx);

    // ---- layer 1: h1 = x @ W1 (split-precision MFMA) ----
    gemm_mfma<true><<<dim3(1, gM), blk, 0, stream>>>(
        (const void*)x, w1t_hi, w1t_lo, (u16*)h1, N, 128, 512);
    alpha4_k<<<(N * 4 + 255) / 256, blk, 0, stream>>>(h1, as1, ad1, asv, adv, N);
    agg1_gather_k<<<N, 128, 0, stream>>>(row_ptr, eidx, src, E, asv, adv, h1, b1, out1b);

    // ---- layer 2: h2 = out1b @ W2 (A exact bf16, B split) ----
    gemm_mfma<false><<<dim3(4, gM), blk, 0, stream>>>(
        (const void*)out1b, w2t_hi, w2t_lo, (u16*)h2, N, 512, 128);
    alpha2w_k<<<N, 256, 0, stream>>>(h2, as2, ad2, asv, adv, N);
    agg2_gather_k<<<N, 128, 0, stream>>>(row_ptr, eidx, src, E, asv, adv, h2, b2, embp);

    // ---- head ----
    final_k<<<(N + 3) / 4, blk, 0, stream>>>(embp, Wl, bl, outp, N);
}

// Round 3
// 876.516 us; speedup vs baseline: 1.4559x; 1.2245x over previous
//
#include <hip/hip_runtime.h>
#include <hip/hip_bf16.h>

typedef __hip_bfloat16 bf16;
typedef unsigned short u16;
typedef u16 u16x8 __attribute__((ext_vector_type(8)));
typedef __bf16 bf16x8 __attribute__((ext_vector_type(8)));
typedef float f32x4 __attribute__((ext_vector_type(4)));

__device__ __forceinline__ float tof(float x) { return x; }
__device__ __forceinline__ float tof(bf16 x) { return __bfloat162float(x); }
__device__ __forceinline__ bf16 tobf(float x) { return __float2bfloat16(x); }

// round-to-nearest-even f32 -> bf16 bits (matches __float2bfloat16 for normals)
__device__ __forceinline__ u16 f2bf(float x) {
    unsigned u = __builtin_bit_cast(unsigned, x);
    u += 0x7fffu + ((u >> 16) & 1u);
    return (u16)(u >> 16);
}
__device__ __forceinline__ float bf2f(u16 h) {
    return __builtin_bit_cast(float, (unsigned)h << 16);
}

// ---- W pre-transpose + split: W[K][N] f32 -> Wt_hi/Wt_lo[N][K] bf16 ------
__global__ void tsplit_k(const float* __restrict__ W, int K, int N,
                         u16* __restrict__ hi, u16* __restrict__ lo)
{
    int i = blockIdx.x * blockDim.x + threadIdx.x;
    if (i >= K * N) return;
    int k = i / N, n = i - k * N;
    float v = W[i];
    u16 h = f2bf(v);
    hi[(long)n * K + k] = h;
    lo[(long)n * K + k] = f2bf(v - bf2f(h));
}

// ---- split-precision MFMA GEMM: C[M,Ntot](bf16) = A[M,K] @ B[K,Ntot] ----
// B supplied pre-transposed + hi/lo split: Bhi/Blo[Ntot][K] bf16.
// SPLIT_A:  A is f32, split on the fly (3 MFMAs: ah*bh + al*bh + ah*bl)
// !SPLIT_A: A is bf16 exact              (2 MFMAs: a*bh + a*bl)
// Tile 128x128, BK=64, 256 threads = 4 waves (2x2), 64x64 per wave.
// LDS layout: row-major [128][64] bf16 with 16B-chunk XOR swizzle
// (chunk ^ (row&7)) to kill the stride-128B bank conflict (Guideline 4).
template <bool SPLIT_A>
__global__ __launch_bounds__(256) void gemm_mfma(
    const void* __restrict__ Avoid, const u16* __restrict__ Bhi,
    const u16* __restrict__ Blo, u16* __restrict__ C,
    int M, int Ntot, int K)
{
    __shared__ u16 AsHi[128 * 64];
    __shared__ u16 AsLo[SPLIT_A ? 128 * 64 : 8];
    __shared__ u16 BsHi[128 * 64];
    __shared__ u16 BsLo[128 * 64];
    const int t = threadIdx.x;
    const long bm = (long)blockIdx.y * 128;
    const int bn = blockIdx.x * 128;
    const int srow = t >> 1;      // staging row/col 0..127
    const int skh  = t & 1;       // staging k-half (32 elems)
    const int w  = t >> 6;
    const int wm = (w >> 1) * 64; // wave row base
    const int wn = (w & 1) * 64;  // wave col base
    const int l  = t & 63;
    const int lr = l & 15;        // fragment row/col
    const int lg = l >> 4;        // fragment k-group

    f32x4 acc[4][4];
#pragma unroll
    for (int i = 0; i < 4; ++i)
#pragma unroll
        for (int j = 0; j < 4; ++j) acc[i][j] = {0.f, 0.f, 0.f, 0.f};

    for (int k0 = 0; k0 < K; k0 += 64) {
        // ---- stage A (reg-staged; swizzled LDS writes) ----
        {
            long r = bm + srow;
            bool ok = r < M;
            if (SPLIT_A) {
                const float* A = (const float*)Avoid;
                const float4* ap = (const float4*)(A + r * K + k0 + skh * 32);
#pragma unroll
                for (int c = 0; c < 4; ++c) {
                    float va[8];
                    if (ok) {
                        float4 v0 = ap[c * 2], v1 = ap[c * 2 + 1];
                        va[0] = v0.x; va[1] = v0.y; va[2] = v0.z; va[3] = v0.w;
                        va[4] = v1.x; va[5] = v1.y; va[6] = v1.z; va[7] = v1.w;
                    } else {
#pragma unroll
                        for (int j = 0; j < 8; ++j) va[j] = 0.f;
                    }
                    u16x8 hi, lo;
#pragma unroll
                    for (int j = 0; j < 8; ++j) {
                        u16 h = f2bf(va[j]);
                        hi[j] = h;
                        lo[j] = f2bf(va[j] - bf2f(h));
                    }
                    int off = srow * 128 + ((((skh * 4 + c) ^ (srow & 7))) << 4);
                    *(u16x8*)((char*)AsHi + off) = hi;
                    *(u16x8*)((char*)AsLo + off) = lo;
                }
            } else {
                const u16* A = (const u16*)Avoid;
                const u16x8* ap = (const u16x8*)(A + r * K + k0 + skh * 32);
#pragma unroll
                for (int c = 0; c < 4; ++c) {
                    u16x8 hv = {0, 0, 0, 0, 0, 0, 0, 0};
                    if (ok) hv = ap[c];
                    int off = srow * 128 + ((((skh * 4 + c) ^ (srow & 7))) << 4);
                    *(u16x8*)((char*)AsHi + off) = hv;
                }
            }
        }
        // ---- stage B ----
        {
            const u16x8* bph = (const u16x8*)(Bhi + (long)(bn + srow) * K + k0 + skh * 32);
            const u16x8* bpl = (const u16x8*)(Blo + (long)(bn + srow) * K + k0 + skh * 32);
#pragma unroll
            for (int c = 0; c < 4; ++c) {
                int off = srow * 128 + ((((skh * 4 + c) ^ (srow & 7))) << 4);
                *(u16x8*)((char*)BsHi + off) = bph[c];
                *(u16x8*)((char*)BsLo + off) = bpl[c];
            }
        }
        __syncthreads();
        // ---- MFMA compute ----
#pragma unroll
        for (int ks = 0; ks < 2; ++ks) {
            bf16x8 bh[4], bl[4];
            const int chl = ks * 4 + lg;  // linear 16B chunk 0..7
#pragma unroll
            for (int n = 0; n < 4; ++n) {
                int col = wn + n * 16 + lr;
                int off = col * 128 + (((chl ^ (col & 7))) << 4);
                bh[n] = *(const bf16x8*)((const char*)BsHi + off);
                bl[n] = *(const bf16x8*)((const char*)BsLo + off);
            }
#pragma unroll
            for (int m = 0; m < 4; ++m) {
                int row = wm + m * 16 + lr;
                int off = row * 128 + (((chl ^ (row & 7))) << 4);
                bf16x8 ah = *(const bf16x8*)((const char*)AsHi + off);
#pragma unroll
                for (int n = 0; n < 4; ++n)
                    acc[m][n] = __builtin_amdgcn_mfma_f32_16x16x32_bf16(
                        ah, bh[n], acc[m][n], 0, 0, 0);
#pragma unroll
                for (int n = 0; n < 4; ++n)
                    acc[m][n] = __builtin_amdgcn_mfma_f32_16x16x32_bf16(
                        ah, bl[n], acc[m][n], 0, 0, 0);
                if (SPLIT_A) {
                    bf16x8 al = *(const bf16x8*)((const char*)AsLo + off);
#pragma unroll
                    for (int n = 0; n < 4; ++n)
                        acc[m][n] = __builtin_amdgcn_mfma_f32_16x16x32_bf16(
                            al, bh[n], acc[m][n], 0, 0, 0);
                }
            }
        }
        __syncthreads();
    }
    // ---- C write: D(reg i, lane l) = C[base + lg*4 + i][base + lr] ----
#pragma unroll
    for (int m = 0; m < 4; ++m) {
        long r0 = bm + wm + m * 16 + lg * 4;
#pragma unroll
        for (int i = 0; i < 4; ++i) {
            long r = r0 + i;
            if (r < M) {
#pragma unroll
                for (int n = 0; n < 4; ++n) {
                    int col = bn + wn + n * 16 + lr;
                    C[r * Ntot + col] = f2bf(acc[m][n][i]);
                }
            }
        }
    }
}

// ---- layer-1 attention logits, 4 heads of C=32: [N,4] -------------------
__global__ void alpha4_k(const bf16* __restrict__ h, const float* __restrict__ asrc,
                         const float* __restrict__ adst, float* __restrict__ out_s,
                         float* __restrict__ out_d, int N)
{
    int i = blockIdx.x * blockDim.x + threadIdx.x;
    if (i >= N * 4) return;
    int n = i >> 2, hh = i & 3;
    const bf16* row = h + (long)n * 128 + hh * 32;
    const float* av = asrc + hh * 32;
    const float* bv = adst + hh * 32;
    float s1 = 0.f, s2 = 0.f;
    for (int c = 0; c < 32; ++c) {
        float v = tof(row[c]);
        s1 += v * av[c];
        s2 += v * bv[c];
    }
    out_s[i] = s1;
    out_d[i] = s2;
}

// ---- layer-2 attention logits: one wave per (node, head), C=128 ---------
__global__ __launch_bounds__(256) void alpha2w_k(
    const bf16* __restrict__ h2, const float* __restrict__ as2,
    const float* __restrict__ ad2, float* __restrict__ out_s,
    float* __restrict__ out_d, int N)
{
    int n = blockIdx.x;
    int w = threadIdx.x >> 6;   // head
    int l = threadIdx.x & 63;
    const bf16* row = h2 + (long)n * 512 + w * 128;
    float v0 = tof(row[l]), v1 = tof(row[l + 64]);
    float s1 = v0 * as2[w * 128 + l] + v1 * as2[w * 128 + l + 64];
    float s2 = v0 * ad2[w * 128 + l] + v1 * ad2[w * 128 + l + 64];
#pragma unroll
    for (int off = 32; off; off >>= 1) {
        s1 += __shfl_down(s1, off);
        s2 += __shfl_down(s2, off);
    }
    if (l == 0) { out_s[n * 4 + w] = s1; out_d[n * 4 + w] = s2; }
}

// ---- CSR build ----------------------------------------------------------
__global__ void init_cnt_k(int* __restrict__ cnt, int N)
{
    int i = blockIdx.x * blockDim.x + threadIdx.x;
    if (i < N) cnt[i] = 1;  // self-loop
}

__global__ void hist_k(const int* __restrict__ dst, int E, int* __restrict__ cnt)
{
    int e = blockIdx.x * blockDim.x + threadIdx.x;
    if (e < E) atomicAdd(&cnt[dst[e]], 1);
}

__global__ __launch_bounds__(256) void scan_blk_k(const int* __restrict__ cnt,
                                                  int* __restrict__ row_ptr,
                                                  int* __restrict__ bsum, int N)
{
    __shared__ int s[256];
    int t = threadIdx.x;
    int i = blockIdx.x * 256 + t;
    int v = (i < N) ? cnt[i] : 0;
    s[t] = v;
    __syncthreads();
    for (int off = 1; off < 256; off <<= 1) {
        int x = (t >= off) ? s[t - off] : 0;
        __syncthreads();
        s[t] += x;
        __syncthreads();
    }
    if (i < N) row_ptr[i] = s[t] - v;  // exclusive
    if (t == 255) bsum[blockIdx.x] = s[255];
}

__global__ __launch_bounds__(512) void scan_top_k(const int* __restrict__ bsum,
                                                  int* __restrict__ bofs, int B)
{
    __shared__ int s[512];
    int t = threadIdx.x;
    int v = (t < B) ? bsum[t] : 0;
    s[t] = v;
    __syncthreads();
    for (int off = 1; off < 512; off <<= 1) {
        int x = (t >= off) ? s[t - off] : 0;
        __syncthreads();
        s[t] += x;
        __syncthreads();
    }
    bofs[t] = s[t] - v;  // exclusive
}

__global__ void add_off_k(int* __restrict__ row_ptr, const int* __restrict__ bofs,
                          int* __restrict__ wofs, int N, int Etot)
{
    int i = blockIdx.x * blockDim.x + threadIdx.x;
    if (i == 0) row_ptr[N] = Etot;
    if (i >= N) return;
    int r = row_ptr[i] + bofs[i >> 8];
    row_ptr[i] = r;
    wofs[i] = r;
}

// stores the RESOLVED source index (not the edge id): one less dependent
// indirection in every downstream edge loop.
__global__ void scatter_k(const int* __restrict__ dst, const int* __restrict__ src,
                          int E, int Etot,
                          int* __restrict__ wofs, int* __restrict__ sidx)
{
    int e = blockIdx.x * blockDim.x + threadIdx.x;
    if (e >= Etot) return;
    int d, s;
    if (e < E) { d = dst[e]; s = src[e]; }
    else       { d = e - E;  s = d; }
    int pos = atomicAdd(&wofs[d], 1);
    sidx[pos] = s;
}

// ---- per-(node,head) edge softmax: writes NORMALIZED alpha per edge -----
// aw[j*4+h] for CSR position j. One thread per (node,head); 3 short loops.
__global__ void edgew_k(const int* __restrict__ row_ptr, const int* __restrict__ sidx,
                        const float* __restrict__ asv, const float* __restrict__ adv,
                        float* __restrict__ aw, int N)
{
    int i = blockIdx.x * blockDim.x + threadIdx.x;
    if (i >= N * 4) return;
    int d = i >> 2, hh = i & 3;
    int beg = row_ptr[d], end = row_ptr[d + 1];
    float ad_d = adv[i];
    float m = -1e30f;
    for (int j = beg; j < end; ++j) {
        float l = asv[sidx[j] * 4 + hh] + ad_d;
        l = l > 0.f ? l : 0.2f * l;
        m = fmaxf(m, l);
    }
    float den = 0.f;
    for (int j = beg; j < end; ++j) {
        float l = asv[sidx[j] * 4 + hh] + ad_d;
        l = l > 0.f ? l : 0.2f * l;
        float w = __expf(l - m);
        den += w;
        aw[(long)j * 4 + hh] = w;
    }
    float inv = 1.f / (den + 1e-16f);
    for (int j = beg; j < end; ++j) aw[(long)j * 4 + hh] *= inv;
}

// ---- layer-1: pure weighted gather + bias + ELU -------------------------
// block = one dst node, 128 threads = output channels (head = t>>5).
__global__ __launch_bounds__(128) void agg1_gather_k(
    const int* __restrict__ row_ptr, const int* __restrict__ sidx,
    const float* __restrict__ aw,
    const bf16* __restrict__ h1, const float* __restrict__ b1,
    bf16* __restrict__ out1b)
{
    int d = blockIdx.x;
    int t = threadIdx.x;
    int hh = t >> 5;
    int beg = row_ptr[d], end = row_ptr[d + 1];
    float acc = 0.f;
    for (int j = beg; j < end; ++j) {
        int s = sidx[j];
        float a = aw[(long)j * 4 + hh];
        acc += a * tof(h1[(long)s * 128 + t]);
    }
    float v = acc + b1[t];
    v = v > 0.f ? v : (__expf(v) - 1.f);
    out1b[(long)d * 128 + t] = tobf(v);
}

// ---- layer-2: pure 4-head weighted gather + head-mean + bias ------------
// block = one dst node, 128 threads = channels c; writes emb f32 directly.
__global__ __launch_bounds__(128) void agg2_gather_k(
    const int* __restrict__ row_ptr, const int* __restrict__ sidx,
    const float* __restrict__ aw,
    const bf16* __restrict__ h2, const float* __restrict__ b2,
    float* __restrict__ emb)
{
    int d = blockIdx.x;
    int c = threadIdx.x;
    int beg = row_ptr[d], end = row_ptr[d + 1];
    float acc = 0.f;
    for (int j = beg; j < end; ++j) {
        int s = sidx[j];
        float4 w = *(const float4*)&aw[(long)j * 4];
        const bf16* hrow = h2 + (long)s * 512 + c;
        acc += w.x * tof(hrow[0]);
        acc += w.y * tof(hrow[128]);
        acc += w.z * tof(hrow[256]);
        acc += w.w * tof(hrow[384]);
    }
    emb[(long)d * 128 + c] = 0.25f * acc + b2[c];
}

// ---- final linear: out[N,64] = emb[N,128] @ W_lin + b -------------------
__global__ __launch_bounds__(256) void final_k(const float* __restrict__ emb,
                                               const float* __restrict__ W,
                                               const float* __restrict__ bias,
                                               float* __restrict__ out, int N)
{
    __shared__ float Ws[128 * 64];
    __shared__ float Es[4][132];
    const int tid = threadIdx.x;
    for (int i = tid; i < 128 * 64; i += 256) Ws[i] = W[i];
    int node0 = blockIdx.x * 4;
    for (int i = tid; i < 512; i += 256) {
        int nn = i >> 7, c = i & 127;
        int n = node0 + nn;
        Es[nn][c] = (n < N) ? emb[(long)n * 128 + c] : 0.f;
    }
    __syncthreads();
    int nn = tid >> 6, j = tid & 63;
    int n = node0 + nn;
    if (n >= N) return;
    float acc = bias[j];
#pragma unroll 8
    for (int k = 0; k < 128; ++k) acc += Es[nn][k] * Ws[k * 64 + j];
    out[(long)n * 64 + j] = acc;
}

// ---- diagnostic ---------------------------------------------------------
__global__ void diag_k(float* __restrict__ out, long n, float val)
{
    long i = (long)blockIdx.x * blockDim.x + threadIdx.x;
    if (i >= n) return;
    out[i] = val;
}

extern "C" void kernel_launch(void* const* d_in, const int* in_sizes, int n_in,
                              void* d_out, int out_size, void* d_ws, size_t ws_size,
                              hipStream_t stream)
{
    const float* x   = (const float*)d_in[0];
    const int* ei    = (const int*)d_in[1];
    const float* W1  = (const float*)d_in[2];
    const float* as1 = (const float*)d_in[3];
    const float* ad1 = (const float*)d_in[4];
    const float* b1  = (const float*)d_in[5];
    const float* W2  = (const float*)d_in[6];
    const float* as2 = (const float*)d_in[7];
    const float* ad2 = (const float*)d_in[8];
    const float* b2  = (const float*)d_in[9];
    const float* Wl  = (const float*)d_in[10];
    const float* bl  = (const float*)d_in[11];

    const int N = in_sizes[0] / 512;
    const int E = in_sizes[1] / 2;
    const int Etot = E + N;
    const int* src = ei;
    const int* dst = ei + E;

    float* outp = (float*)d_out;          // [N,64]
    float* embp = outp + (size_t)N * 64;  // [N,128] f32
    // out1b (bf16 [N,128]) parked inside the embp region (dead before agg2 writes emb)
    bf16* out1b = (bf16*)embp;
    // normalized edge weights [Etot,4] f32 parked in outp (dead until final_k;
    // agg kernels consume aw strictly before final_k writes outp). 11.2MB <= 25.6MB.
    float* aw = outp;

    // ---- workspace layout (~107 MB; known-safe floor from R3 diag = 119.6 MB) ----
    char* wsb = (char*)d_ws;
    bf16*  h2    = (bf16*)wsb;                              // N*512 bf16
    bf16*  h1    = (bf16*)wsb;                              // N*128 bf16 (alias)
    float* asv   = (float*)(wsb + (size_t)N * 512 * sizeof(bf16));  // N*4
    float* adv   = asv + (size_t)N * 4;                     // N*4
    int*   cnt   = (int*)(adv + (size_t)N * 4);             // N
    int*   row_ptr = cnt + N;                               // N+1
    int*   wofs  = row_ptr + (N + 1);                       // N
    int*   bsum  = wofs + N;                                // 512
    int*   bofs  = bsum + 512;                              // 512
    int*   sidx  = bofs + 512;                              // Etot (resolved src)
    // transposed + hi/lo-split weights (bf16), 256B-aligned
    char*  pw    = (char*)(sidx + Etot);
    pw = (char*)(((uintptr_t)pw + 255) & ~(uintptr_t)255);
    u16*   w1t_hi = (u16*)pw;                               // [128][512]
    u16*   w1t_lo = w1t_hi + 128 * 512;
    u16*   w2t_hi = w1t_lo + 128 * 512;                     // [512][128]
    u16*   w2t_lo = w2t_hi + 512 * 128;
    size_t need  = (size_t)((char*)(w2t_lo + 512 * 128) - wsb);

    dim3 blk(256);
    long n_out_total = (long)N * 192;

    if (ws_size < need) {
        float val = 100.0f + (float)(ws_size >> 20);
        diag_k<<<(int)((n_out_total + 255) / 256), blk, 0, stream>>>(outp, n_out_total, val);
        return;
    }

    const int B = (N + 255) / 256;  // scan blocks (<=512 for N<=131072)
    const int gM = (N + 127) / 128; // MFMA gemm row-blocks

    // ---- weight transpose+split (tiny, independent of everything) ----
    tsplit_k<<<(512 * 128 + 255) / 256, blk, 0, stream>>>(W1, 512, 128, w1t_hi, w1t_lo);
    tsplit_k<<<(128 * 512 + 255) / 256, blk, 0, stream>>>(W2, 128, 512, w2t_hi, w2t_lo);

    // ---- CSR build (by dst) ----
    init_cnt_k<<<B, blk, 0, stream>>>(cnt, N);
    hist_k<<<(E + 255) / 256, blk, 0, stream>>>(dst, E, cnt);
    scan_blk_k<<<B, blk, 0, stream>>>(cnt, row_ptr, bsum, N);
    scan_top_k<<<1, 512, 0, stream>>>(bsum, bofs, B);
    add_off_k<<<B, blk, 0, stream>>>(row_ptr, bofs, wofs, N, Etot);
    scatter_k<<<(Etot + 255) / 256, blk, 0, stream>>>(dst, src, E, Etot, wofs, sidx);

    // ---- layer 1: h1 = x @ W1 (split-precision MFMA) ----
    gemm_mfma<true><<<dim3(1, gM), blk, 0, stream>>>(
        (const void*)x, w1t_hi, w1t_lo, (u16*)h1, N, 128, 512);
    alpha4_k<<<(N * 4 + 255) / 256, blk, 0, stream>>>(h1, as1, ad1, asv, adv, N);
    edgew_k<<<(N * 4 + 255) / 256, blk, 0, stream>>>(row_ptr, sidx, asv, adv, aw, N);
    agg1_gather_k<<<N, 128, 0, stream>>>(row_ptr, sidx, aw, h1, b1, out1b);

    // ---- layer 2: h2 = out1b @ W2 (A exact bf16, B split) ----
    gemm_mfma<false><<<dim3(4, gM), blk, 0, stream>>>(
        (const void*)out1b, w2t_hi, w2t_lo, (u16*)h2, N, 512, 128);
    alpha2w_k<<<N, 256, 0, stream>>>(h2, as2, ad2, asv, adv, N);
    edgew_k<<<(N * 4 + 255) / 256, blk, 0, stream>>>(row_ptr, sidx, asv, adv, aw, N);
    agg2_gather_k<<<N, 128, 0, stream>>>(row_ptr, sidx, aw, h2, b2, embp);

    // ---- head ----
    final_k<<<(N + 3) / 4, blk, 0, stream>>>(embp, Wl, bl, outp, N);
}

// Round 4
// 850.758 us; speedup vs baseline: 1.4999x; 1.0303x over previous
//
#include <hip/hip_runtime.h>
#include <hip/hip_bf16.h>

typedef __hip_bfloat16 bf16;
typedef unsigned short u16;
typedef unsigned int u32;
typedef u16 u16x8 __attribute__((ext_vector_type(8)));
typedef __bf16 bf16x8 __attribute__((ext_vector_type(8)));
typedef float f32x4 __attribute__((ext_vector_type(4)));

__device__ __forceinline__ float tof(float x) { return x; }
__device__ __forceinline__ float tof(bf16 x) { return __bfloat162float(x); }
__device__ __forceinline__ bf16 tobf(float x) { return __float2bfloat16(x); }

// round-to-nearest-even f32 -> bf16 bits (matches __float2bfloat16 for normals)
__device__ __forceinline__ u16 f2bf(float x) {
    unsigned u = __builtin_bit_cast(unsigned, x);
    u += 0x7fffu + ((u >> 16) & 1u);
    return (u16)(u >> 16);
}
__device__ __forceinline__ float bf2f(u16 h) {
    return __builtin_bit_cast(float, (unsigned)h << 16);
}
// unpack a uint holding two consecutive bf16 (little-endian): lo = even ch, hi = odd ch
__device__ __forceinline__ float bflo(u32 u) {
    return __builtin_bit_cast(float, u << 16);
}
__device__ __forceinline__ float bfhi(u32 u) {
    return __builtin_bit_cast(float, u & 0xffff0000u);
}

// ---- W pre-transpose + split: W[K][N] f32 -> Wt_hi/Wt_lo[N][K] bf16 ------
__global__ void tsplit_k(const float* __restrict__ W, int K, int N,
                         u16* __restrict__ hi, u16* __restrict__ lo)
{
    int i = blockIdx.x * blockDim.x + threadIdx.x;
    if (i >= K * N) return;
    int k = i / N, n = i - k * N;
    float v = W[i];
    u16 h = f2bf(v);
    hi[(long)n * K + k] = h;
    lo[(long)n * K + k] = f2bf(v - bf2f(h));
}

// ---- split-precision MFMA GEMM: C[M,Ntot](bf16) = A[M,K] @ B[K,Ntot] ----
// B supplied pre-transposed + hi/lo split: Bhi/Blo[Ntot][K] bf16.
// SPLIT_A:  A is f32, split on the fly (3 MFMAs: ah*bh + al*bh + ah*bl)
// !SPLIT_A: A is bf16 exact              (2 MFMAs: a*bh + a*bl)
// Tile 128x128, BK=64, 256 threads = 4 waves (2x2), 64x64 per wave.
// LDS layout: row-major [128][64] bf16 with 16B-chunk XOR swizzle
// (chunk ^ (row&7)) to kill the stride-128B bank conflict (Guideline 4).
template <bool SPLIT_A>
__global__ __launch_bounds__(256) void gemm_mfma(
    const void* __restrict__ Avoid, const u16* __restrict__ Bhi,
    const u16* __restrict__ Blo, u16* __restrict__ C,
    int M, int Ntot, int K)
{
    __shared__ u16 AsHi[128 * 64];
    __shared__ u16 AsLo[SPLIT_A ? 128 * 64 : 8];
    __shared__ u16 BsHi[128 * 64];
    __shared__ u16 BsLo[128 * 64];
    const int t = threadIdx.x;
    const long bm = (long)blockIdx.y * 128;
    const int bn = blockIdx.x * 128;
    const int srow = t >> 1;      // staging row/col 0..127
    const int skh  = t & 1;       // staging k-half (32 elems)
    const int w  = t >> 6;
    const int wm = (w >> 1) * 64; // wave row base
    const int wn = (w & 1) * 64;  // wave col base
    const int l  = t & 63;
    const int lr = l & 15;        // fragment row/col
    const int lg = l >> 4;        // fragment k-group

    f32x4 acc[4][4];
#pragma unroll
    for (int i = 0; i < 4; ++i)
#pragma unroll
        for (int j = 0; j < 4; ++j) acc[i][j] = {0.f, 0.f, 0.f, 0.f};

    for (int k0 = 0; k0 < K; k0 += 64) {
        // ---- stage A (reg-staged; swizzled LDS writes) ----
        {
            long r = bm + srow;
            bool ok = r < M;
            if (SPLIT_A) {
                const float* A = (const float*)Avoid;
                const float4* ap = (const float4*)(A + r * K + k0 + skh * 32);
#pragma unroll
                for (int c = 0; c < 4; ++c) {
                    float va[8];
                    if (ok) {
                        float4 v0 = ap[c * 2], v1 = ap[c * 2 + 1];
                        va[0] = v0.x; va[1] = v0.y; va[2] = v0.z; va[3] = v0.w;
                        va[4] = v1.x; va[5] = v1.y; va[6] = v1.z; va[7] = v1.w;
                    } else {
#pragma unroll
                        for (int j = 0; j < 8; ++j) va[j] = 0.f;
                    }
                    u16x8 hi, lo;
#pragma unroll
                    for (int j = 0; j < 8; ++j) {
                        u16 h = f2bf(va[j]);
                        hi[j] = h;
                        lo[j] = f2bf(va[j] - bf2f(h));
                    }
                    int off = srow * 128 + ((((skh * 4 + c) ^ (srow & 7))) << 4);
                    *(u16x8*)((char*)AsHi + off) = hi;
                    *(u16x8*)((char*)AsLo + off) = lo;
                }
            } else {
                const u16* A = (const u16*)Avoid;
                const u16x8* ap = (const u16x8*)(A + r * K + k0 + skh * 32);
#pragma unroll
                for (int c = 0; c < 4; ++c) {
                    u16x8 hv = {0, 0, 0, 0, 0, 0, 0, 0};
                    if (ok) hv = ap[c];
                    int off = srow * 128 + ((((skh * 4 + c) ^ (srow & 7))) << 4);
                    *(u16x8*)((char*)AsHi + off) = hv;
                }
            }
        }
        // ---- stage B ----
        {
            const u16x8* bph = (const u16x8*)(Bhi + (long)(bn + srow) * K + k0 + skh * 32);
            const u16x8* bpl = (const u16x8*)(Blo + (long)(bn + srow) * K + k0 + skh * 32);
#pragma unroll
            for (int c = 0; c < 4; ++c) {
                int off = srow * 128 + ((((skh * 4 + c) ^ (srow & 7))) << 4);
                *(u16x8*)((char*)BsHi + off) = bph[c];
                *(u16x8*)((char*)BsLo + off) = bpl[c];
            }
        }
        __syncthreads();
        // ---- MFMA compute ----
#pragma unroll
        for (int ks = 0; ks < 2; ++ks) {
            bf16x8 bh[4], bl[4];
            const int chl = ks * 4 + lg;  // linear 16B chunk 0..7
#pragma unroll
            for (int n = 0; n < 4; ++n) {
                int col = wn + n * 16 + lr;
                int off = col * 128 + (((chl ^ (col & 7))) << 4);
                bh[n] = *(const bf16x8*)((const char*)BsHi + off);
                bl[n] = *(const bf16x8*)((const char*)BsLo + off);
            }
#pragma unroll
            for (int m = 0; m < 4; ++m) {
                int row = wm + m * 16 + lr;
                int off = row * 128 + (((chl ^ (row & 7))) << 4);
                bf16x8 ah = *(const bf16x8*)((const char*)AsHi + off);
#pragma unroll
                for (int n = 0; n < 4; ++n)
                    acc[m][n] = __builtin_amdgcn_mfma_f32_16x16x32_bf16(
                        ah, bh[n], acc[m][n], 0, 0, 0);
#pragma unroll
                for (int n = 0; n < 4; ++n)
                    acc[m][n] = __builtin_amdgcn_mfma_f32_16x16x32_bf16(
                        ah, bl[n], acc[m][n], 0, 0, 0);
                if (SPLIT_A) {
                    bf16x8 al = *(const bf16x8*)((const char*)AsLo + off);
#pragma unroll
                    for (int n = 0; n < 4; ++n)
                        acc[m][n] = __builtin_amdgcn_mfma_f32_16x16x32_bf16(
                            al, bh[n], acc[m][n], 0, 0, 0);
                }
            }
        }
        __syncthreads();
    }
    // ---- C write: D(reg i, lane l) = C[base + lg*4 + i][base + lr] ----
#pragma unroll
    for (int m = 0; m < 4; ++m) {
        long r0 = bm + wm + m * 16 + lg * 4;
#pragma unroll
        for (int i = 0; i < 4; ++i) {
            long r = r0 + i;
            if (r < M) {
#pragma unroll
                for (int n = 0; n < 4; ++n) {
                    int col = bn + wn + n * 16 + lr;
                    C[r * Ntot + col] = f2bf(acc[m][n][i]);
                }
            }
        }
    }
}

// ---- layer-1 attention logits, 4 heads of C=32: [N,4] -------------------
__global__ void alpha4_k(const bf16* __restrict__ h, const float* __restrict__ asrc,
                         const float* __restrict__ adst, float* __restrict__ out_s,
                         float* __restrict__ out_d, int N)
{
    int i = blockIdx.x * blockDim.x + threadIdx.x;
    if (i >= N * 4) return;
    int n = i >> 2, hh = i & 3;
    const bf16* row = h + (long)n * 128 + hh * 32;
    const float* av = asrc + hh * 32;
    const float* bv = adst + hh * 32;
    float s1 = 0.f, s2 = 0.f;
    for (int c = 0; c < 32; ++c) {
        float v = tof(row[c]);
        s1 += v * av[c];
        s2 += v * bv[c];
    }
    out_s[i] = s1;
    out_d[i] = s2;
}

// ---- layer-2 attention logits: one wave per (node, head), C=128 ---------
__global__ __launch_bounds__(256) void alpha2w_k(
    const bf16* __restrict__ h2, const float* __restrict__ as2,
    const float* __restrict__ ad2, float* __restrict__ out_s,
    float* __restrict__ out_d, int N)
{
    int n = blockIdx.x;
    int w = threadIdx.x >> 6;   // head
    int l = threadIdx.x & 63;
    const bf16* row = h2 + (long)n * 512 + w * 128;
    float v0 = tof(row[l]), v1 = tof(row[l + 64]);
    float s1 = v0 * as2[w * 128 + l] + v1 * as2[w * 128 + l + 64];
    float s2 = v0 * ad2[w * 128 + l] + v1 * ad2[w * 128 + l + 64];
#pragma unroll
    for (int off = 32; off; off >>= 1) {
        s1 += __shfl_down(s1, off);
        s2 += __shfl_down(s2, off);
    }
    if (l == 0) { out_s[n * 4 + w] = s1; out_d[n * 4 + w] = s2; }
}

// ---- CSR build ----------------------------------------------------------
__global__ void init_cnt_k(int* __restrict__ cnt, int N)
{
    int i = blockIdx.x * blockDim.x + threadIdx.x;
    if (i < N) cnt[i] = 1;  // self-loop
}

__global__ void hist_k(const int* __restrict__ dst, int E, int* __restrict__ cnt)
{
    int e = blockIdx.x * blockDim.x + threadIdx.x;
    if (e < E) atomicAdd(&cnt[dst[e]], 1);
}

__global__ __launch_bounds__(256) void scan_blk_k(const int* __restrict__ cnt,
                                                  int* __restrict__ row_ptr,
                                                  int* __restrict__ bsum, int N)
{
    __shared__ int s[256];
    int t = threadIdx.x;
    int i = blockIdx.x * 256 + t;
    int v = (i < N) ? cnt[i] : 0;
    s[t] = v;
    __syncthreads();
    for (int off = 1; off < 256; off <<= 1) {
        int x = (t >= off) ? s[t - off] : 0;
        __syncthreads();
        s[t] += x;
        __syncthreads();
    }
    if (i < N) row_ptr[i] = s[t] - v;  // exclusive
    if (t == 255) bsum[blockIdx.x] = s[255];
}

__global__ __launch_bounds__(512) void scan_top_k(const int* __restrict__ bsum,
                                                  int* __restrict__ bofs, int B)
{
    __shared__ int s[512];
    int t = threadIdx.x;
    int v = (t < B) ? bsum[t] : 0;
    s[t] = v;
    __syncthreads();
    for (int off = 1; off < 512; off <<= 1) {
        int x = (t >= off) ? s[t - off] : 0;
        __syncthreads();
        s[t] += x;
        __syncthreads();
    }
    bofs[t] = s[t] - v;  // exclusive
}

__global__ void add_off_k(int* __restrict__ row_ptr, const int* __restrict__ bofs,
                          int* __restrict__ wofs, int N, int Etot)
{
    int i = blockIdx.x * blockDim.x + threadIdx.x;
    if (i == 0) row_ptr[N] = Etot;
    if (i >= N) return;
    int r = row_ptr[i] + bofs[i >> 8];
    row_ptr[i] = r;
    wofs[i] = r;
}

// stores the RESOLVED source index (not the edge id): one less dependent
// indirection in every downstream edge loop.
__global__ void scatter_k(const int* __restrict__ dst, const int* __restrict__ src,
                          int E, int Etot,
                          int* __restrict__ wofs, int* __restrict__ sidx)
{
    int e = blockIdx.x * blockDim.x + threadIdx.x;
    if (e >= Etot) return;
    int d, s;
    if (e < E) { d = dst[e]; s = src[e]; }
    else       { d = e - E;  s = d; }
    int pos = atomicAdd(&wofs[d], 1);
    sidx[pos] = s;
}

// ---- per-(node,head) edge softmax: UNNORMALIZED w + 1/den ---------------
// aw[j*4+h] for CSR position j; invden[n*4+h]. Normalization deferred to
// the aggregation epilogue (saves the whole third rescale pass).
__global__ void edgew_k(const int* __restrict__ row_ptr, const int* __restrict__ sidx,
                        const float* __restrict__ asv, const float* __restrict__ adv,
                        float* __restrict__ aw, float* __restrict__ invden, int N)
{
    int i = blockIdx.x * blockDim.x + threadIdx.x;
    if (i >= N * 4) return;
    int d = i >> 2, hh = i & 3;
    int beg = row_ptr[d], end = row_ptr[d + 1];
    float ad_d = adv[i];
    float m = -1e30f;
    for (int j = beg; j < end; ++j) {
        float l = asv[sidx[j] * 4 + hh] + ad_d;
        l = l > 0.f ? l : 0.2f * l;
        m = fmaxf(m, l);
    }
    float den = 0.f;
    for (int j = beg; j < end; ++j) {
        float l = asv[sidx[j] * 4 + hh] + ad_d;
        l = l > 0.f ? l : 0.2f * l;
        float w = __expf(l - m);
        den += w;
        aw[(long)j * 4 + hh] = w;
    }
    invden[i] = 1.f / (den + 1e-16f);
}

// ---- layer-1: weighted gather + deferred norm + bias + ELU --------------
// 256-thread block = 4 nodes, one wave each (no barriers). Thread handles
// 2 consecutive channels via one uint (2x bf16) load per edge.
__global__ __launch_bounds__(256) void agg1_gather_k(
    const int* __restrict__ row_ptr, const int* __restrict__ sidx,
    const float* __restrict__ aw, const float* __restrict__ invden,
    const bf16* __restrict__ h1, const float* __restrict__ b1,
    bf16* __restrict__ out1b, int N)
{
    int d = blockIdx.x * 4 + (threadIdx.x >> 6);
    if (d >= N) return;
    int t = threadIdx.x & 63;
    int c0 = t * 2;
    int hh = t >> 4;              // head of both channels
    int beg = row_ptr[d], end = row_ptr[d + 1];
    float accA = 0.f, accB = 0.f;
    for (int j = beg; j < end; ++j) {
        int s = sidx[j];
        float a = aw[(long)j * 4 + hh];
        u32 u = *(const u32*)((const u16*)h1 + (long)s * 128 + c0);
        accA += a * bflo(u);
        accB += a * bfhi(u);
    }
    float inv = invden[d * 4 + hh];
    float vA = accA * inv + b1[c0];
    float vB = accB * inv + b1[c0 + 1];
    vA = vA > 0.f ? vA : (__expf(vA) - 1.f);
    vB = vB > 0.f ? vB : (__expf(vB) - 1.f);
    u32 packed = (u32)f2bf(vA) | ((u32)f2bf(vB) << 16);
    *(u32*)((u16*)out1b + (long)d * 128 + c0) = packed;
}

// ---- layer-2: 4-head weighted gather + deferred norm + head-mean + bias --
// 256-thread block = 4 nodes; thread handles 2 channels x 4 heads
// (4 uint loads per edge, halving VMEM instruction count vs 2B/lane).
__global__ __launch_bounds__(256) void agg2_gather_k(
    const int* __restrict__ row_ptr, const int* __restrict__ sidx,
    const float* __restrict__ aw, const float* __restrict__ invden,
    const bf16* __restrict__ h2, const float* __restrict__ b2,
    float* __restrict__ emb, int N)
{
    int d = blockIdx.x * 4 + (threadIdx.x >> 6);
    if (d >= N) return;
    int t = threadIdx.x & 63;
    int c0 = t * 2;
    int beg = row_ptr[d], end = row_ptr[d + 1];
    float a0A = 0.f, a0B = 0.f, a1A = 0.f, a1B = 0.f;
    float a2A = 0.f, a2B = 0.f, a3A = 0.f, a3B = 0.f;
    for (int j = beg; j < end; ++j) {
        int s = sidx[j];
        float4 w = *(const float4*)&aw[(long)j * 4];
        const u16* hrow = (const u16*)h2 + (long)s * 512 + c0;
        u32 u0 = *(const u32*)(hrow);
        u32 u1 = *(const u32*)(hrow + 128);
        u32 u2 = *(const u32*)(hrow + 256);
        u32 u3 = *(const u32*)(hrow + 384);
        a0A += w.x * bflo(u0); a0B += w.x * bfhi(u0);
        a1A += w.y * bflo(u1); a1B += w.y * bfhi(u1);
        a2A += w.z * bflo(u2); a2B += w.z * bfhi(u2);
        a3A += w.w * bflo(u3); a3B += w.w * bfhi(u3);
    }
    float4 inv = *(const float4*)&invden[d * 4];
    float eA = 0.25f * (a0A * inv.x + a1A * inv.y + a2A * inv.z + a3A * inv.w) + b2[c0];
    float eB = 0.25f * (a0B * inv.x + a1B * inv.y + a2B * inv.z + a3B * inv.w) + b2[c0 + 1];
    float2 ev = {eA, eB};
    *(float2*)&emb[(long)d * 128 + c0] = ev;
}

// ---- final linear: out[N,64] = emb[N,128] @ W_lin + b -------------------
__global__ __launch_bounds__(256) void final_k(const float* __restrict__ emb,
                                               const float* __restrict__ W,
                                               const float* __restrict__ bias,
                                               float* __restrict__ out, int N)
{
    __shared__ float Ws[128 * 64];
    __shared__ float Es[4][132];
    const int tid = threadIdx.x;
    for (int i = tid; i < 128 * 64; i += 256) Ws[i] = W[i];
    int node0 = blockIdx.x * 4;
    for (int i = tid; i < 512; i += 256) {
        int nn = i >> 7, c = i & 127;
        int n = node0 + nn;
        Es[nn][c] = (n < N) ? emb[(long)n * 128 + c] : 0.f;
    }
    __syncthreads();
    int nn = tid >> 6, j = tid & 63;
    int n = node0 + nn;
    if (n >= N) return;
    float acc = bias[j];
#pragma unroll 8
    for (int k = 0; k < 128; ++k) acc += Es[nn][k] * Ws[k * 64 + j];
    out[(long)n * 64 + j] = acc;
}

// ---- diagnostic ---------------------------------------------------------
__global__ void diag_k(float* __restrict__ out, long n, float val)
{
    long i = (long)blockIdx.x * blockDim.x + threadIdx.x;
    if (i >= n) return;
    out[i] = val;
}

extern "C" void kernel_launch(void* const* d_in, const int* in_sizes, int n_in,
                              void* d_out, int out_size, void* d_ws, size_t ws_size,
                              hipStream_t stream)
{
    const float* x   = (const float*)d_in[0];
    const int* ei    = (const int*)d_in[1];
    const float* W1  = (const float*)d_in[2];
    const float* as1 = (const float*)d_in[3];
    const float* ad1 = (const float*)d_in[4];
    const float* b1  = (const float*)d_in[5];
    const float* W2  = (const float*)d_in[6];
    const float* as2 = (const float*)d_in[7];
    const float* ad2 = (const float*)d_in[8];
    const float* b2  = (const float*)d_in[9];
    const float* Wl  = (const float*)d_in[10];
    const float* bl  = (const float*)d_in[11];

    const int N = in_sizes[0] / 512;
    const int E = in_sizes[1] / 2;
    const int Etot = E + N;
    const int* src = ei;
    const int* dst = ei + E;

    float* outp = (float*)d_out;          // [N,64]
    float* embp = outp + (size_t)N * 64;  // [N,128] f32
    // out1b (bf16 [N,128]) parked inside the embp region (dead before agg2 writes emb)
    bf16* out1b = (bf16*)embp;
    // unnormalized edge weights [Etot,4] f32 parked in outp (dead until final_k;
    // agg kernels consume aw strictly before final_k writes outp). 11.2MB <= 25.6MB.
    float* aw = outp;

    // ---- workspace layout (~109 MB; known-safe floor from R3 diag = 119.6 MB) ----
    char* wsb = (char*)d_ws;
    bf16*  h2    = (bf16*)wsb;                              // N*512 bf16
    bf16*  h1    = (bf16*)wsb;                              // N*128 bf16 (alias)
    float* asv   = (float*)(wsb + (size_t)N * 512 * sizeof(bf16));  // N*4
    float* adv   = asv + (size_t)N * 4;                     // N*4
    float* invden = adv + (size_t)N * 4;                    // N*4
    int*   cnt   = (int*)(invden + (size_t)N * 4);          // N
    int*   row_ptr = cnt + N;                               // N+1
    int*   wofs  = row_ptr + (N + 1);                       // N
    int*   bsum  = wofs + N;                                // 512
    int*   bofs  = bsum + 512;                              // 512
    int*   sidx  = bofs + 512;                              // Etot (resolved src)
    // transposed + hi/lo-split weights (bf16), 256B-aligned
    char*  pw    = (char*)(sidx + Etot);
    pw = (char*)(((uintptr_t)pw + 255) & ~(uintptr_t)255);
    u16*   w1t_hi = (u16*)pw;                               // [128][512]
    u16*   w1t_lo = w1t_hi + 128 * 512;
    u16*   w2t_hi = w1t_lo + 128 * 512;                     // [512][128]
    u16*   w2t_lo = w2t_hi + 512 * 128;
    size_t need  = (size_t)((char*)(w2t_lo + 512 * 128) - wsb);

    dim3 blk(256);
    long n_out_total = (long)N * 192;

    if (ws_size < need) {
        float val = 100.0f + (float)(ws_size >> 20);
        diag_k<<<(int)((n_out_total + 255) / 256), blk, 0, stream>>>(outp, n_out_total, val);
        return;
    }

    const int B = (N + 255) / 256;  // scan blocks (<=512 for N<=131072)
    const int gM = (N + 127) / 128; // MFMA gemm row-blocks
    const int gAgg = (N + 3) / 4;   // agg blocks (4 nodes per 256-thread block)

    // ---- weight transpose+split (tiny, independent of everything) ----
    tsplit_k<<<(512 * 128 + 255) / 256, blk, 0, stream>>>(W1, 512, 128, w1t_hi, w1t_lo);
    tsplit_k<<<(128 * 512 + 255) / 256, blk, 0, stream>>>(W2, 128, 512, w2t_hi, w2t_lo);

    // ---- CSR build (by dst) ----
    init_cnt_k<<<B, blk, 0, stream>>>(cnt, N);
    hist_k<<<(E + 255) / 256, blk, 0, stream>>>(dst, E, cnt);
    scan_blk_k<<<B, blk, 0, stream>>>(cnt, row_ptr, bsum, N);
    scan_top_k<<<1, 512, 0, stream>>>(bsum, bofs, B);
    add_off_k<<<B, blk, 0, stream>>>(row_ptr, bofs, wofs, N, Etot);
    scatter_k<<<(Etot + 255) / 256, blk, 0, stream>>>(dst, src, E, Etot, wofs, sidx);

    // ---- layer 1: h1 = x @ W1 (split-precision MFMA) ----
    gemm_mfma<true><<<dim3(1, gM), blk, 0, stream>>>(
        (const void*)x, w1t_hi, w1t_lo, (u16*)h1, N, 128, 512);
    alpha4_k<<<(N * 4 + 255) / 256, blk, 0, stream>>>(h1, as1, ad1, asv, adv, N);
    edgew_k<<<(N * 4 + 255) / 256, blk, 0, stream>>>(row_ptr, sidx, asv, adv, aw, invden, N);
    agg1_gather_k<<<gAgg, blk, 0, stream>>>(row_ptr, sidx, aw, invden, h1, b1, out1b, N);

    // ---- layer 2: h2 = out1b @ W2 (A exact bf16, B split) ----
    gemm_mfma<false><<<dim3(4, gM), blk, 0, stream>>>(
        (const void*)out1b, w2t_hi, w2t_lo, (u16*)h2, N, 512, 128);
    alpha2w_k<<<N, 256, 0, stream>>>(h2, as2, ad2, asv, adv, N);
    edgew_k<<<(N * 4 + 255) / 256, blk, 0, stream>>>(row_ptr, sidx, asv, adv, aw, invden, N);
    agg2_gather_k<<<gAgg, blk, 0, stream>>>(row_ptr, sidx, aw, invden, h2, b2, embp, N);

    // ---- head ----
    final_k<<<(N + 3) / 4, blk, 0, stream>>>(embp, Wl, bl, outp, N);
}

// Round 5
// 844.739 us; speedup vs baseline: 1.5106x; 1.0071x over previous
//
#include <hip/hip_runtime.h>
#include <hip/hip_bf16.h>

typedef __hip_bfloat16 bf16;
typedef unsigned short u16;
typedef unsigned int u32;
typedef u16 u16x8 __attribute__((ext_vector_type(8)));
typedef __bf16 bf16x8 __attribute__((ext_vector_type(8)));
typedef float f32x4 __attribute__((ext_vector_type(4)));

__device__ __forceinline__ float tof(float x) { return x; }
__device__ __forceinline__ float tof(bf16 x) { return __bfloat162float(x); }
__device__ __forceinline__ bf16 tobf(float x) { return __float2bfloat16(x); }

// round-to-nearest-even f32 -> bf16 bits (matches __float2bfloat16 for normals)
__device__ __forceinline__ u16 f2bf(float x) {
    unsigned u = __builtin_bit_cast(unsigned, x);
    u += 0x7fffu + ((u >> 16) & 1u);
    return (u16)(u >> 16);
}
__device__ __forceinline__ float bf2f(u16 h) {
    return __builtin_bit_cast(float, (unsigned)h << 16);
}
// unpack a uint holding two consecutive bf16 (little-endian): lo = even ch, hi = odd ch
__device__ __forceinline__ float bflo(u32 u) {
    return __builtin_bit_cast(float, u << 16);
}
__device__ __forceinline__ float bfhi(u32 u) {
    return __builtin_bit_cast(float, u & 0xffff0000u);
}
// C-store helpers for the GEMM epilogue
__device__ __forceinline__ void cstore(u16* p, float v) { *p = f2bf(v); }
__device__ __forceinline__ void cstore(float* p, float v) { *p = v; }

// ---- W pre-transpose + split: W[K][N] f32 -> Wt_hi/Wt_lo[N][K] bf16 ------
__global__ void tsplit_k(const float* __restrict__ W, int K, int N,
                         u16* __restrict__ hi, u16* __restrict__ lo)
{
    int i = blockIdx.x * blockDim.x + threadIdx.x;
    if (i >= K * N) return;
    int k = i / N, n = i - k * N;
    float v = W[i];
    u16 h = f2bf(v);
    hi[(long)n * K + k] = h;
    lo[(long)n * K + k] = f2bf(v - bf2f(h));
}

// ---- permuted split for layer-2: Bp[h*128+c, o] = W2[c, h*128+o] --------
// stored transposed for the GEMM B-operand: Bpt[o][h*128+c], ld=512.
__global__ void tsplit2_k(const float* __restrict__ W2,
                          u16* __restrict__ hi, u16* __restrict__ lo)
{
    int i = blockIdx.x * blockDim.x + threadIdx.x;
    if (i >= 128 * 512) return;
    int c = i >> 9, o2 = i & 511;          // W2 is [128][512]
    int hh = o2 >> 7, o = o2 & 127;
    float v = W2[i];
    u16 h = f2bf(v);
    long dsti = (long)o * 512 + hh * 128 + c;
    hi[dsti] = h;
    lo[dsti] = f2bf(v - bf2f(h));
}

// ---- V = per-head W2_h @ a2_h: Vs/Vd[h*128+c] ---------------------------
__global__ void vmat_k(const float* __restrict__ W2, const float* __restrict__ as2,
                       const float* __restrict__ ad2,
                       float* __restrict__ Vs, float* __restrict__ Vd)
{
    int i = blockIdx.x * blockDim.x + threadIdx.x;
    if (i >= 512) return;
    int hh = i >> 7, c = i & 127;
    float s = 0.f, d = 0.f;
    const float* wrow = W2 + (long)c * 512 + hh * 128;
    const float* ar = as2 + hh * 128;
    const float* br = ad2 + hh * 128;
    for (int o = 0; o < 128; ++o) {
        float w = wrow[o];
        s += w * ar[o];
        d += w * br[o];
    }
    Vs[i] = s;
    Vd[i] = d;
}

// ---- split-precision MFMA GEMM: C[M,Ntot] = A[M,K] @ B[K,Ntot] (+bias) --
// B supplied pre-transposed + hi/lo split: Bhi/Blo[Ntot][K] bf16.
// SPLIT_A:  A is f32, split on the fly (3 MFMAs: ah*bh + al*bh + ah*bl)
// !SPLIT_A: A is bf16 exact              (2 MFMAs: a*bh + a*bl)
// TC: u16 (bf16 store) or float (f32 store). Optional bias[Ntot].
// Tile 128x128, BK=64, 256 threads = 4 waves (2x2), 64x64 per wave.
// LDS: row-major [128][64] bf16 with 16B-chunk XOR swizzle (Guideline 4).
template <bool SPLIT_A, typename TC>
__global__ __launch_bounds__(256) void gemm_mfma(
    const void* __restrict__ Avoid, const u16* __restrict__ Bhi,
    const u16* __restrict__ Blo, TC* __restrict__ C,
    int M, int Ntot, int K, const float* __restrict__ bias)
{
    __shared__ u16 AsHi[128 * 64];
    __shared__ u16 AsLo[SPLIT_A ? 128 * 64 : 8];
    __shared__ u16 BsHi[128 * 64];
    __shared__ u16 BsLo[128 * 64];
    const int t = threadIdx.x;
    const long bm = (long)blockIdx.y * 128;
    const int bn = blockIdx.x * 128;
    const int srow = t >> 1;      // staging row/col 0..127
    const int skh  = t & 1;       // staging k-half (32 elems)
    const int w  = t >> 6;
    const int wm = (w >> 1) * 64; // wave row base
    const int wn = (w & 1) * 64;  // wave col base
    const int l  = t & 63;
    const int lr = l & 15;        // fragment row/col
    const int lg = l >> 4;        // fragment k-group

    f32x4 acc[4][4];
#pragma unroll
    for (int i = 0; i < 4; ++i)
#pragma unroll
        for (int j = 0; j < 4; ++j) acc[i][j] = {0.f, 0.f, 0.f, 0.f};

    for (int k0 = 0; k0 < K; k0 += 64) {
        // ---- stage A (reg-staged; swizzled LDS writes) ----
        {
            long r = bm + srow;
            bool ok = r < M;
            if (SPLIT_A) {
                const float* A = (const float*)Avoid;
                const float4* ap = (const float4*)(A + r * K + k0 + skh * 32);
#pragma unroll
                for (int c = 0; c < 4; ++c) {
                    float va[8];
                    if (ok) {
                        float4 v0 = ap[c * 2], v1 = ap[c * 2 + 1];
                        va[0] = v0.x; va[1] = v0.y; va[2] = v0.z; va[3] = v0.w;
                        va[4] = v1.x; va[5] = v1.y; va[6] = v1.z; va[7] = v1.w;
                    } else {
#pragma unroll
                        for (int j = 0; j < 8; ++j) va[j] = 0.f;
                    }
                    u16x8 hi, lo;
#pragma unroll
                    for (int j = 0; j < 8; ++j) {
                        u16 h = f2bf(va[j]);
                        hi[j] = h;
                        lo[j] = f2bf(va[j] - bf2f(h));
                    }
                    int off = srow * 128 + ((((skh * 4 + c) ^ (srow & 7))) << 4);
                    *(u16x8*)((char*)AsHi + off) = hi;
                    *(u16x8*)((char*)AsLo + off) = lo;
                }
            } else {
                const u16* A = (const u16*)Avoid;
                const u16x8* ap = (const u16x8*)(A + r * K + k0 + skh * 32);
#pragma unroll
                for (int c = 0; c < 4; ++c) {
                    u16x8 hv = {0, 0, 0, 0, 0, 0, 0, 0};
                    if (ok) hv = ap[c];
                    int off = srow * 128 + ((((skh * 4 + c) ^ (srow & 7))) << 4);
                    *(u16x8*)((char*)AsHi + off) = hv;
                }
            }
        }
        // ---- stage B ----
        {
            const u16x8* bph = (const u16x8*)(Bhi + (long)(bn + srow) * K + k0 + skh * 32);
            const u16x8* bpl = (const u16x8*)(Blo + (long)(bn + srow) * K + k0 + skh * 32);
#pragma unroll
            for (int c = 0; c < 4; ++c) {
                int off = srow * 128 + ((((skh * 4 + c) ^ (srow & 7))) << 4);
                *(u16x8*)((char*)BsHi + off) = bph[c];
                *(u16x8*)((char*)BsLo + off) = bpl[c];
            }
        }
        __syncthreads();
        // ---- MFMA compute ----
#pragma unroll
        for (int ks = 0; ks < 2; ++ks) {
            bf16x8 bh[4], bl[4];
            const int chl = ks * 4 + lg;  // linear 16B chunk 0..7
#pragma unroll
            for (int n = 0; n < 4; ++n) {
                int col = wn + n * 16 + lr;
                int off = col * 128 + (((chl ^ (col & 7))) << 4);
                bh[n] = *(const bf16x8*)((const char*)BsHi + off);
                bl[n] = *(const bf16x8*)((const char*)BsLo + off);
            }
#pragma unroll
            for (int m = 0; m < 4; ++m) {
                int row = wm + m * 16 + lr;
                int off = row * 128 + (((chl ^ (row & 7))) << 4);
                bf16x8 ah = *(const bf16x8*)((const char*)AsHi + off);
#pragma unroll
                for (int n = 0; n < 4; ++n)
                    acc[m][n] = __builtin_amdgcn_mfma_f32_16x16x32_bf16(
                        ah, bh[n], acc[m][n], 0, 0, 0);
#pragma unroll
                for (int n = 0; n < 4; ++n)
                    acc[m][n] = __builtin_amdgcn_mfma_f32_16x16x32_bf16(
                        ah, bl[n], acc[m][n], 0, 0, 0);
                if (SPLIT_A) {
                    bf16x8 al = *(const bf16x8*)((const char*)AsLo + off);
#pragma unroll
                    for (int n = 0; n < 4; ++n)
                        acc[m][n] = __builtin_amdgcn_mfma_f32_16x16x32_bf16(
                            al, bh[n], acc[m][n], 0, 0, 0);
                }
            }
        }
        __syncthreads();
    }
    // ---- C write: D(reg i, lane l) = C[base + lg*4 + i][base + lr] ----
#pragma unroll
    for (int m = 0; m < 4; ++m) {
        long r0 = bm + wm + m * 16 + lg * 4;
#pragma unroll
        for (int i = 0; i < 4; ++i) {
            long r = r0 + i;
            if (r < M) {
#pragma unroll
                for (int n = 0; n < 4; ++n) {
                    int col = bn + wn + n * 16 + lr;
                    float v = acc[m][n][i];
                    if (bias) v += bias[col];
                    cstore(&C[r * Ntot + col], v);
                }
            }
        }
    }
}

// ---- layer-1 attention logits, 4 heads of C=32: [N,4] -------------------
__global__ void alpha4_k(const bf16* __restrict__ h, const float* __restrict__ asrc,
                         const float* __restrict__ adst, float* __restrict__ out_s,
                         float* __restrict__ out_d, int N)
{
    int i = blockIdx.x * blockDim.x + threadIdx.x;
    if (i >= N * 4) return;
    int n = i >> 2, hh = i & 3;
    const bf16* row = h + (long)n * 128 + hh * 32;
    const float* av = asrc + hh * 32;
    const float* bv = adst + hh * 32;
    float s1 = 0.f, s2 = 0.f;
    for (int c = 0; c < 32; ++c) {
        float v = tof(row[c]);
        s1 += v * av[c];
        s2 += v * bv[c];
    }
    out_s[i] = s1;
    out_d[i] = s2;
}

// ---- layer-2 attention logits from out1b via composite V ----------------
// alpha_s[n,h] = out1b[n,:] . Vs[h*128:...], same for d. No h2 needed.
__global__ void alpha2v_k(const bf16* __restrict__ out1b, const float* __restrict__ Vs,
                          const float* __restrict__ Vd, float* __restrict__ out_s,
                          float* __restrict__ out_d, int N)
{
    int i = blockIdx.x * blockDim.x + threadIdx.x;
    if (i >= N * 4) return;
    int n = i >> 2, hh = i & 3;
    const u32* rp = (const u32*)((const u16*)out1b + (long)n * 128);
    const float* vs = Vs + hh * 128;
    const float* vd = Vd + hh * 128;
    float s1 = 0.f, s2 = 0.f;
#pragma unroll 8
    for (int c2 = 0; c2 < 64; ++c2) {
        u32 u = rp[c2];
        float lo = bflo(u), hi = bfhi(u);
        s1 += lo * vs[c2 * 2] + hi * vs[c2 * 2 + 1];
        s2 += lo * vd[c2 * 2] + hi * vd[c2 * 2 + 1];
    }
    out_s[i] = s1;
    out_d[i] = s2;
}

// ---- CSR build ----------------------------------------------------------
__global__ void init_cnt_k(int* __restrict__ cnt, int N)
{
    int i = blockIdx.x * blockDim.x + threadIdx.x;
    if (i < N) cnt[i] = 1;  // self-loop
}

__global__ void hist_k(const int* __restrict__ dst, int E, int* __restrict__ cnt)
{
    int e = blockIdx.x * blockDim.x + threadIdx.x;
    if (e < E) atomicAdd(&cnt[dst[e]], 1);
}

__global__ __launch_bounds__(256) void scan_blk_k(const int* __restrict__ cnt,
                                                  int* __restrict__ row_ptr,
                                                  int* __restrict__ bsum, int N)
{
    __shared__ int s[256];
    int t = threadIdx.x;
    int i = blockIdx.x * 256 + t;
    int v = (i < N) ? cnt[i] : 0;
    s[t] = v;
    __syncthreads();
    for (int off = 1; off < 256; off <<= 1) {
        int x = (t >= off) ? s[t - off] : 0;
        __syncthreads();
        s[t] += x;
        __syncthreads();
    }
    if (i < N) row_ptr[i] = s[t] - v;  // exclusive
    if (t == 255) bsum[blockIdx.x] = s[255];
}

__global__ __launch_bounds__(512) void scan_top_k(const int* __restrict__ bsum,
                                                  int* __restrict__ bofs, int B)
{
    __shared__ int s[512];
    int t = threadIdx.x;
    int v = (t < B) ? bsum[t] : 0;
    s[t] = v;
    __syncthreads();
    for (int off = 1; off < 512; off <<= 1) {
        int x = (t >= off) ? s[t - off] : 0;
        __syncthreads();
        s[t] += x;
        __syncthreads();
    }
    bofs[t] = s[t] - v;  // exclusive
}

__global__ void add_off_k(int* __restrict__ row_ptr, const int* __restrict__ bofs,
                          int* __restrict__ wofs, int N, int Etot)
{
    int i = blockIdx.x * blockDim.x + threadIdx.x;
    if (i == 0) row_ptr[N] = Etot;
    if (i >= N) return;
    int r = row_ptr[i] + bofs[i >> 8];
    row_ptr[i] = r;
    wofs[i] = r;
}

// stores the RESOLVED source index (not the edge id): one less dependent
// indirection in every downstream edge loop.
__global__ void scatter_k(const int* __restrict__ dst, const int* __restrict__ src,
                          int E, int Etot,
                          int* __restrict__ wofs, int* __restrict__ sidx)
{
    int e = blockIdx.x * blockDim.x + threadIdx.x;
    if (e >= Etot) return;
    int d, s;
    if (e < E) { d = dst[e]; s = src[e]; }
    else       { d = e - E;  s = d; }
    int pos = atomicAdd(&wofs[d], 1);
    sidx[pos] = s;
}

// ---- per-(node,head) edge softmax: UNNORMALIZED w + 1/den ---------------
__global__ void edgew_k(const int* __restrict__ row_ptr, const int* __restrict__ sidx,
                        const float* __restrict__ asv, const float* __restrict__ adv,
                        float* __restrict__ aw, float* __restrict__ invden, int N)
{
    int i = blockIdx.x * blockDim.x + threadIdx.x;
    if (i >= N * 4) return;
    int d = i >> 2, hh = i & 3;
    int beg = row_ptr[d], end = row_ptr[d + 1];
    float ad_d = adv[i];
    float m = -1e30f;
    for (int j = beg; j < end; ++j) {
        float l = asv[sidx[j] * 4 + hh] + ad_d;
        l = l > 0.f ? l : 0.2f * l;
        m = fmaxf(m, l);
    }
    float den = 0.f;
    for (int j = beg; j < end; ++j) {
        float l = asv[sidx[j] * 4 + hh] + ad_d;
        l = l > 0.f ? l : 0.2f * l;
        float w = __expf(l - m);
        den += w;
        aw[(long)j * 4 + hh] = w;
    }
    invden[i] = 1.f / (den + 1e-16f);
}

// ---- layer-1: weighted gather + deferred norm + bias + ELU --------------
// 256-thread block = 4 nodes, one wave each. Thread = 2 channels (u32 load).
__global__ __launch_bounds__(256) void agg1_gather_k(
    const int* __restrict__ row_ptr, const int* __restrict__ sidx,
    const float* __restrict__ aw, const float* __restrict__ invden,
    const bf16* __restrict__ h1, const float* __restrict__ b1,
    bf16* __restrict__ out1b, int N)
{
    int d = blockIdx.x * 4 + (threadIdx.x >> 6);
    if (d >= N) return;
    int t = threadIdx.x & 63;
    int c0 = t * 2;
    int hh = t >> 4;              // head of both channels
    int beg = row_ptr[d], end = row_ptr[d + 1];
    float accA = 0.f, accB = 0.f;
    for (int j = beg; j < end; ++j) {
        int s = sidx[j];
        float a = aw[(long)j * 4 + hh];
        u32 u = *(const u32*)((const u16*)h1 + (long)s * 128 + c0);
        accA += a * bflo(u);
        accB += a * bfhi(u);
    }
    float inv = invden[d * 4 + hh];
    float vA = accA * inv + b1[c0];
    float vB = accB * inv + b1[c0 + 1];
    vA = vA > 0.f ? vA : (__expf(vA) - 1.f);
    vB = vB > 0.f ? vB : (__expf(vB) - 1.f);
    u32 packed = (u32)f2bf(vA) | ((u32)f2bf(vB) << 16);
    *(u32*)((u16*)out1b + (long)d * 128 + c0) = packed;
}

// ---- layer-2 aggregation over out1b (NOT h2): Z[d,h*128+c] --------------
// Z = 0.25 * inv_h * sum_e alpha_h(e) * out1b[src(e), c], bf16 [N,512].
// One u32 (2ch) gather per edge serves all 4 heads. out1b is 25.6MB -> L2.
__global__ __launch_bounds__(256) void agg2z_gather_k(
    const int* __restrict__ row_ptr, const int* __restrict__ sidx,
    const float* __restrict__ aw, const float* __restrict__ invden,
    const bf16* __restrict__ out1b, u16* __restrict__ Z, int N)
{
    int d = blockIdx.x * 4 + (threadIdx.x >> 6);
    if (d >= N) return;
    int t = threadIdx.x & 63;
    int c0 = t * 2;
    int beg = row_ptr[d], end = row_ptr[d + 1];
    float a0A = 0.f, a0B = 0.f, a1A = 0.f, a1B = 0.f;
    float a2A = 0.f, a2B = 0.f, a3A = 0.f, a3B = 0.f;
    for (int j = beg; j < end; ++j) {
        int s = sidx[j];
        float4 w = *(const float4*)&aw[(long)j * 4];
        u32 u = *(const u32*)((const u16*)out1b + (long)s * 128 + c0);
        float lo = bflo(u), hi = bfhi(u);
        a0A += w.x * lo; a0B += w.x * hi;
        a1A += w.y * lo; a1B += w.y * hi;
        a2A += w.z * lo; a2B += w.z * hi;
        a3A += w.w * lo; a3B += w.w * hi;
    }
    float4 inv = *(const float4*)&invden[d * 4];
    u16* zrow = Z + (long)d * 512 + c0;
    float s0A = 0.25f * inv.x * a0A, s0B = 0.25f * inv.x * a0B;
    float s1A = 0.25f * inv.y * a1A, s1B = 0.25f * inv.y * a1B;
    float s2A = 0.25f * inv.z * a2A, s2B = 0.25f * inv.z * a2B;
    float s3A = 0.25f * inv.w * a3A, s3B = 0.25f * inv.w * a3B;
    *(u32*)(zrow)       = (u32)f2bf(s0A) | ((u32)f2bf(s0B) << 16);
    *(u32*)(zrow + 128) = (u32)f2bf(s1A) | ((u32)f2bf(s1B) << 16);
    *(u32*)(zrow + 256) = (u32)f2bf(s2A) | ((u32)f2bf(s2B) << 16);
    *(u32*)(zrow + 384) = (u32)f2bf(s3A) | ((u32)f2bf(s3B) << 16);
}

// ---- final linear: out[N,64] = emb[N,128] @ W_lin + b -------------------
__global__ __launch_bounds__(256) void final_k(const float* __restrict__ emb,
                                               const float* __restrict__ W,
                                               const float* __restrict__ bias,
                                               float* __restrict__ out, int N)
{
    __shared__ float Ws[128 * 64];
    __shared__ float Es[4][132];
    const int tid = threadIdx.x;
    for (int i = tid; i < 128 * 64; i += 256) Ws[i] = W[i];
    int node0 = blockIdx.x * 4;
    for (int i = tid; i < 512; i += 256) {
        int nn = i >> 7, c = i & 127;
        int n = node0 + nn;
        Es[nn][c] = (n < N) ? emb[(long)n * 128 + c] : 0.f;
    }
    __syncthreads();
    int nn = tid >> 6, j = tid & 63;
    int n = node0 + nn;
    if (n >= N) return;
    float acc = bias[j];
#pragma unroll 8
    for (int k = 0; k < 128; ++k) acc += Es[nn][k] * Ws[k * 64 + j];
    out[(long)n * 64 + j] = acc;
}

// ---- diagnostic ---------------------------------------------------------
__global__ void diag_k(float* __restrict__ out, long n, float val)
{
    long i = (long)blockIdx.x * blockDim.x + threadIdx.x;
    if (i >= n) return;
    out[i] = val;
}

extern "C" void kernel_launch(void* const* d_in, const int* in_sizes, int n_in,
                              void* d_out, int out_size, void* d_ws, size_t ws_size,
                              hipStream_t stream)
{
    const float* x   = (const float*)d_in[0];
    const int* ei    = (const int*)d_in[1];
    const float* W1  = (const float*)d_in[2];
    const float* as1 = (const float*)d_in[3];
    const float* ad1 = (const float*)d_in[4];
    const float* b1  = (const float*)d_in[5];
    const float* W2  = (const float*)d_in[6];
    const float* as2 = (const float*)d_in[7];
    const float* ad2 = (const float*)d_in[8];
    const float* b2  = (const float*)d_in[9];
    const float* Wl  = (const float*)d_in[10];
    const float* bl  = (const float*)d_in[11];

    const int N = in_sizes[0] / 512;
    const int E = in_sizes[1] / 2;
    const int Etot = E + N;
    const int* src = ei;
    const int* dst = ei + E;

    float* outp = (float*)d_out;          // [N,64]
    float* embp = outp + (size_t)N * 64;  // [N,128] f32
    // out1b (bf16 [N,128]) parked inside the embp region (dead before gemm2 writes emb)
    bf16* out1b = (bf16*)embp;
    // unnormalized edge weights [Etot,4] f32 parked in outp (dead until final_k)
    float* aw = outp;

    // ---- workspace layout (~109 MB; known-safe floor from R3 diag = 119.6 MB) ----
    char* wsb = (char*)d_ws;
    u16*   Z     = (u16*)wsb;                               // N*512 bf16 (layer-2 aggregate)
    bf16*  h1    = (bf16*)wsb;                              // N*128 bf16 (alias; dead before Z written)
    float* asv   = (float*)(wsb + (size_t)N * 512 * sizeof(u16));   // N*4
    float* adv   = asv + (size_t)N * 4;                     // N*4
    float* invden = adv + (size_t)N * 4;                    // N*4
    int*   cnt   = (int*)(invden + (size_t)N * 4);          // N
    int*   row_ptr = cnt + N;                               // N+1
    int*   wofs  = row_ptr + (N + 1);                       // N
    int*   bsum  = wofs + N;                                // 512
    int*   bofs  = bsum + 512;                              // 512
    int*   sidx  = bofs + 512;                              // Etot (resolved src)
    // transposed + hi/lo-split weights (bf16), 256B-aligned
    char*  pw    = (char*)(sidx + Etot);
    pw = (char*)(((uintptr_t)pw + 255) & ~(uintptr_t)255);
    u16*   w1t_hi = (u16*)pw;                               // [128][512]
    u16*   w1t_lo = w1t_hi + 128 * 512;
    u16*   w2t_hi = w1t_lo + 128 * 512;                     // [128][512] permuted W2
    u16*   w2t_lo = w2t_hi + 512 * 128;
    float* Vs    = (float*)(w2t_lo + 512 * 128);            // 512
    float* Vd    = Vs + 512;                                // 512
    size_t need  = (size_t)((char*)(Vd + 512) - wsb);

    dim3 blk(256);
    long n_out_total = (long)N * 192;

    if (ws_size < need) {
        float val = 100.0f + (float)(ws_size >> 20);
        diag_k<<<(int)((n_out_total + 255) / 256), blk, 0, stream>>>(outp, n_out_total, val);
        return;
    }

    const int B = (N + 255) / 256;  // scan blocks (<=512 for N<=131072)
    const int gM = (N + 127) / 128; // MFMA gemm row-blocks
    const int gAgg = (N + 3) / 4;   // agg blocks (4 nodes per 256-thread block)

    // ---- weight prep (tiny, independent of everything) ----
    tsplit_k<<<(512 * 128 + 255) / 256, blk, 0, stream>>>(W1, 512, 128, w1t_hi, w1t_lo);
    tsplit2_k<<<(128 * 512 + 255) / 256, blk, 0, stream>>>(W2, w2t_hi, w2t_lo);
    vmat_k<<<2, blk, 0, stream>>>(W2, as2, ad2, Vs, Vd);

    // ---- CSR build (by dst) ----
    init_cnt_k<<<B, blk, 0, stream>>>(cnt, N);
    hist_k<<<(E + 255) / 256, blk, 0, stream>>>(dst, E, cnt);
    scan_blk_k<<<B, blk, 0, stream>>>(cnt, row_ptr, bsum, N);
    scan_top_k<<<1, 512, 0, stream>>>(bsum, bofs, B);
    add_off_k<<<B, blk, 0, stream>>>(row_ptr, bofs, wofs, N, Etot);
    scatter_k<<<(Etot + 255) / 256, blk, 0, stream>>>(dst, src, E, Etot, wofs, sidx);

    // ---- layer 1: h1 = x @ W1 (split-precision MFMA) ----
    gemm_mfma<true, u16><<<dim3(1, gM), blk, 0, stream>>>(
        (const void*)x, w1t_hi, w1t_lo, (u16*)h1, N, 128, 512, nullptr);
    alpha4_k<<<(N * 4 + 255) / 256, blk, 0, stream>>>(h1, as1, ad1, asv, adv, N);
    edgew_k<<<(N * 4 + 255) / 256, blk, 0, stream>>>(row_ptr, sidx, asv, adv, aw, invden, N);
    agg1_gather_k<<<gAgg, blk, 0, stream>>>(row_ptr, sidx, aw, invden, h1, b1, out1b, N);

    // ---- layer 2 (h2 never materialized) ----
    // logits via composite V; aggregate out1b -> Z; emb = Z @ Bp + b2 (MFMA).
    alpha2v_k<<<(N * 4 + 255) / 256, blk, 0, stream>>>(out1b, Vs, Vd, asv, adv, N);
    edgew_k<<<(N * 4 + 255) / 256, blk, 0, stream>>>(row_ptr, sidx, asv, adv, aw, invden, N);
    agg2z_gather_k<<<gAgg, blk, 0, stream>>>(row_ptr, sidx, aw, invden, out1b, Z, N);
    gemm_mfma<false, float><<<dim3(1, gM), blk, 0, stream>>>(
        (const void*)Z, w2t_hi, w2t_lo, embp, N, 128, 512, b2);

    // ---- head ----
    final_k<<<(N + 3) / 4, blk, 0, stream>>>(embp, Wl, bl, outp, N);
}

// Round 6
// 745.878 us; speedup vs baseline: 1.7109x; 1.1325x over previous
//
#include <hip/hip_runtime.h>
#include <hip/hip_bf16.h>

typedef __hip_bfloat16 bf16;
typedef unsigned short u16;
typedef unsigned int u32;
typedef u16 u16x8 __attribute__((ext_vector_type(8)));
typedef u32 u32x2 __attribute__((ext_vector_type(2)));
typedef __bf16 bf16x8 __attribute__((ext_vector_type(8)));
typedef float f32x4 __attribute__((ext_vector_type(4)));

__device__ __forceinline__ float tof(bf16 x) { return __bfloat162float(x); }

// round-to-nearest-even f32 -> bf16 bits (matches __float2bfloat16 for normals)
__device__ __forceinline__ u16 f2bf(float x) {
    unsigned u = __builtin_bit_cast(unsigned, x);
    u += 0x7fffu + ((u >> 16) & 1u);
    return (u16)(u >> 16);
}
__device__ __forceinline__ float bf2f(u16 h) {
    return __builtin_bit_cast(float, (unsigned)h << 16);
}
// unpack a uint holding two consecutive bf16: lo = even ch, hi = odd ch
__device__ __forceinline__ float bflo(u32 u) {
    return __builtin_bit_cast(float, u << 16);
}
__device__ __forceinline__ float bfhi(u32 u) {
    return __builtin_bit_cast(float, u & 0xffff0000u);
}
// C-store helpers for the GEMM epilogue
__device__ __forceinline__ void cstore(u16* p, float v) { *p = f2bf(v); }
__device__ __forceinline__ void cstore(float* p, float v) { *p = v; }

// ---- W pre-transpose + split: W[K][N] f32 -> Wt_hi/Wt_lo[N][K] bf16 ------
__global__ void tsplit_k(const float* __restrict__ W, int K, int N,
                         u16* __restrict__ hi, u16* __restrict__ lo)
{
    int i = blockIdx.x * blockDim.x + threadIdx.x;
    if (i >= K * N) return;
    int k = i / N, n = i - k * N;
    float v = W[i];
    u16 h = f2bf(v);
    hi[(long)n * K + k] = h;
    lo[(long)n * K + k] = f2bf(v - bf2f(h));
}

// ---- permuted split for layer-2: Bpt[o][h*128+c] = W2[c, h*128+o] -------
__global__ void tsplit2_k(const float* __restrict__ W2,
                          u16* __restrict__ hi, u16* __restrict__ lo)
{
    int i = blockIdx.x * blockDim.x + threadIdx.x;
    if (i >= 128 * 512) return;
    int c = i >> 9, o2 = i & 511;          // W2 is [128][512]
    int hh = o2 >> 7, o = o2 & 127;
    float v = W2[i];
    u16 h = f2bf(v);
    long dsti = (long)o * 512 + hh * 128 + c;
    hi[dsti] = h;
    lo[dsti] = f2bf(v - bf2f(h));
}

// ---- V = per-head W2_h @ a2_h: Vs/Vd[h*128+c] ---------------------------
__global__ void vmat_k(const float* __restrict__ W2, const float* __restrict__ as2,
                       const float* __restrict__ ad2,
                       float* __restrict__ Vs, float* __restrict__ Vd)
{
    int i = blockIdx.x * blockDim.x + threadIdx.x;
    if (i >= 512) return;
    int hh = i >> 7, c = i & 127;
    float s = 0.f, d = 0.f;
    const float* wrow = W2 + (long)c * 512 + hh * 128;
    const float* ar = as2 + hh * 128;
    const float* br = ad2 + hh * 128;
    for (int o = 0; o < 128; ++o) {
        float w = wrow[o];
        s += w * ar[o];
        d += w * br[o];
    }
    Vs[i] = s;
    Vd[i] = d;
}

// ---- split-precision MFMA GEMM: C[M,Ntot] = A[M,K] @ B[K,Ntot] (+bias) --
template <bool SPLIT_A, typename TC>
__global__ __launch_bounds__(256) void gemm_mfma(
    const void* __restrict__ Avoid, const u16* __restrict__ Bhi,
    const u16* __restrict__ Blo, TC* __restrict__ C,
    int M, int Ntot, int K, const float* __restrict__ bias)
{
    __shared__ u16 AsHi[128 * 64];
    __shared__ u16 AsLo[SPLIT_A ? 128 * 64 : 8];
    __shared__ u16 BsHi[128 * 64];
    __shared__ u16 BsLo[128 * 64];
    const int t = threadIdx.x;
    const long bm = (long)blockIdx.y * 128;
    const int bn = blockIdx.x * 128;
    const int srow = t >> 1;      // staging row/col 0..127
    const int skh  = t & 1;       // staging k-half (32 elems)
    const int w  = t >> 6;
    const int wm = (w >> 1) * 64; // wave row base
    const int wn = (w & 1) * 64;  // wave col base
    const int l  = t & 63;
    const int lr = l & 15;        // fragment row/col
    const int lg = l >> 4;        // fragment k-group

    f32x4 acc[4][4];
#pragma unroll
    for (int i = 0; i < 4; ++i)
#pragma unroll
        for (int j = 0; j < 4; ++j) acc[i][j] = {0.f, 0.f, 0.f, 0.f};

    for (int k0 = 0; k0 < K; k0 += 64) {
        // ---- stage A (reg-staged; swizzled LDS writes) ----
        {
            long r = bm + srow;
            bool ok = r < M;
            if (SPLIT_A) {
                const float* A = (const float*)Avoid;
                const float4* ap = (const float4*)(A + r * K + k0 + skh * 32);
#pragma unroll
                for (int c = 0; c < 4; ++c) {
                    float va[8];
                    if (ok) {
                        float4 v0 = ap[c * 2], v1 = ap[c * 2 + 1];
                        va[0] = v0.x; va[1] = v0.y; va[2] = v0.z; va[3] = v0.w;
                        va[4] = v1.x; va[5] = v1.y; va[6] = v1.z; va[7] = v1.w;
                    } else {
#pragma unroll
                        for (int j = 0; j < 8; ++j) va[j] = 0.f;
                    }
                    u16x8 hi, lo;
#pragma unroll
                    for (int j = 0; j < 8; ++j) {
                        u16 h = f2bf(va[j]);
                        hi[j] = h;
                        lo[j] = f2bf(va[j] - bf2f(h));
                    }
                    int off = srow * 128 + ((((skh * 4 + c) ^ (srow & 7))) << 4);
                    *(u16x8*)((char*)AsHi + off) = hi;
                    *(u16x8*)((char*)AsLo + off) = lo;
                }
            } else {
                const u16* A = (const u16*)Avoid;
                const u16x8* ap = (const u16x8*)(A + r * K + k0 + skh * 32);
#pragma unroll
                for (int c = 0; c < 4; ++c) {
                    u16x8 hv = {0, 0, 0, 0, 0, 0, 0, 0};
                    if (ok) hv = ap[c];
                    int off = srow * 128 + ((((skh * 4 + c) ^ (srow & 7))) << 4);
                    *(u16x8*)((char*)AsHi + off) = hv;
                }
            }
        }
        // ---- stage B ----
        {
            const u16x8* bph = (const u16x8*)(Bhi + (long)(bn + srow) * K + k0 + skh * 32);
            const u16x8* bpl = (const u16x8*)(Blo + (long)(bn + srow) * K + k0 + skh * 32);
#pragma unroll
            for (int c = 0; c < 4; ++c) {
                int off = srow * 128 + ((((skh * 4 + c) ^ (srow & 7))) << 4);
                *(u16x8*)((char*)BsHi + off) = bph[c];
                *(u16x8*)((char*)BsLo + off) = bpl[c];
            }
        }
        __syncthreads();
        // ---- MFMA compute ----
#pragma unroll
        for (int ks = 0; ks < 2; ++ks) {
            bf16x8 bh[4], bl[4];
            const int chl = ks * 4 + lg;  // linear 16B chunk 0..7
#pragma unroll
            for (int n = 0; n < 4; ++n) {
                int col = wn + n * 16 + lr;
                int off = col * 128 + (((chl ^ (col & 7))) << 4);
                bh[n] = *(const bf16x8*)((const char*)BsHi + off);
                bl[n] = *(const bf16x8*)((const char*)BsLo + off);
            }
#pragma unroll
            for (int m = 0; m < 4; ++m) {
                int row = wm + m * 16 + lr;
                int off = row * 128 + (((chl ^ (row & 7))) << 4);
                bf16x8 ah = *(const bf16x8*)((const char*)AsHi + off);
#pragma unroll
                for (int n = 0; n < 4; ++n)
                    acc[m][n] = __builtin_amdgcn_mfma_f32_16x16x32_bf16(
                        ah, bh[n], acc[m][n], 0, 0, 0);
#pragma unroll
                for (int n = 0; n < 4; ++n)
                    acc[m][n] = __builtin_amdgcn_mfma_f32_16x16x32_bf16(
                        ah, bl[n], acc[m][n], 0, 0, 0);
                if (SPLIT_A) {
                    bf16x8 al = *(const bf16x8*)((const char*)AsLo + off);
#pragma unroll
                    for (int n = 0; n < 4; ++n)
                        acc[m][n] = __builtin_amdgcn_mfma_f32_16x16x32_bf16(
                            al, bh[n], acc[m][n], 0, 0, 0);
                }
            }
        }
        __syncthreads();
    }
    // ---- C write: D(reg i, lane l) = C[base + lg*4 + i][base + lr] ----
#pragma unroll
    for (int m = 0; m < 4; ++m) {
        long r0 = bm + wm + m * 16 + lg * 4;
#pragma unroll
        for (int i = 0; i < 4; ++i) {
            long r = r0 + i;
            if (r < M) {
#pragma unroll
                for (int n = 0; n < 4; ++n) {
                    int col = bn + wn + n * 16 + lr;
                    float v = acc[m][n][i];
                    if (bias) v += bias[col];
                    cstore(&C[r * Ntot + col], v);
                }
            }
        }
    }
}

// ---- layer-1 attention logits, 4 heads of C=32: [N,4] -------------------
__global__ void alpha4_k(const bf16* __restrict__ h, const float* __restrict__ asrc,
                         const float* __restrict__ adst, float* __restrict__ out_s,
                         float* __restrict__ out_d, int N)
{
    int i = blockIdx.x * blockDim.x + threadIdx.x;
    if (i >= N * 4) return;
    int n = i >> 2, hh = i & 3;
    const bf16* row = h + (long)n * 128 + hh * 32;
    const float* av = asrc + hh * 32;
    const float* bv = adst + hh * 32;
    float s1 = 0.f, s2 = 0.f;
    for (int c = 0; c < 32; ++c) {
        float v = tof(row[c]);
        s1 += v * av[c];
        s2 += v * bv[c];
    }
    out_s[i] = s1;
    out_d[i] = s2;
}

// ---- CSR build ----------------------------------------------------------
__global__ void init_cnt_k(int* __restrict__ cnt, int N)
{
    int i = blockIdx.x * blockDim.x + threadIdx.x;
    if (i < N) cnt[i] = 1;  // self-loop
}

__global__ void hist_k(const int* __restrict__ dst, int E, int* __restrict__ cnt)
{
    int e = blockIdx.x * blockDim.x + threadIdx.x;
    if (e < E) atomicAdd(&cnt[dst[e]], 1);
}

__global__ __launch_bounds__(256) void scan_blk_k(const int* __restrict__ cnt,
                                                  int* __restrict__ row_ptr,
                                                  int* __restrict__ bsum, int N)
{
    __shared__ int s[256];
    int t = threadIdx.x;
    int i = blockIdx.x * 256 + t;
    int v = (i < N) ? cnt[i] : 0;
    s[t] = v;
    __syncthreads();
    for (int off = 1; off < 256; off <<= 1) {
        int x = (t >= off) ? s[t - off] : 0;
        __syncthreads();
        s[t] += x;
        __syncthreads();
    }
    if (i < N) row_ptr[i] = s[t] - v;  // exclusive
    if (t == 255) bsum[blockIdx.x] = s[255];
}

__global__ __launch_bounds__(512) void scan_top_k(const int* __restrict__ bsum,
                                                  int* __restrict__ bofs, int B)
{
    __shared__ int s[512];
    int t = threadIdx.x;
    int v = (t < B) ? bsum[t] : 0;
    s[t] = v;
    __syncthreads();
    for (int off = 1; off < 512; off <<= 1) {
        int x = (t >= off) ? s[t - off] : 0;
        __syncthreads();
        s[t] += x;
        __syncthreads();
    }
    bofs[t] = s[t] - v;  // exclusive
}

__global__ void add_off_k(int* __restrict__ row_ptr, const int* __restrict__ bofs,
                          int* __restrict__ wofs, int N, int Etot)
{
    int i = blockIdx.x * blockDim.x + threadIdx.x;
    if (i == 0) row_ptr[N] = Etot;
    if (i >= N) return;
    int r = row_ptr[i] + bofs[i >> 8];
    row_ptr[i] = r;
    wofs[i] = r;
}

// stores the RESOLVED source index (not the edge id)
__global__ void scatter_k(const int* __restrict__ dst, const int* __restrict__ src,
                          int E, int Etot,
                          int* __restrict__ wofs, int* __restrict__ sidx)
{
    int e = blockIdx.x * blockDim.x + threadIdx.x;
    if (e >= Etot) return;
    int d, s;
    if (e < E) { d = dst[e]; s = src[e]; }
    else       { d = e - E;  s = d; }
    int pos = atomicAdd(&wofs[d], 1);
    sidx[pos] = s;
}

// ---- layer-1 FUSED: online-softmax + gather + norm + bias + ELU + L2 logits
// 32-lane group per dst node (8 nodes / 256-thread block, no barriers).
// Phase A (per chunk of 32 edges): lane j owns edge j -> logits, shfl-reduce
// max/den with flash-style rescale. Phase B: lanes own 4 channels each,
// per-edge weight broadcast via __shfl, 8B u32x2 gathers from h1.
// Epilogue also computes layer-2 logits (dot with Vs/Vd + 32-lane reduce),
// eliminating the separate alpha2v pass.
__global__ __launch_bounds__(256) void agg1f_k(
    const int* __restrict__ row_ptr, const int* __restrict__ sidx,
    const float* __restrict__ asv, const float* __restrict__ adv,
    const bf16* __restrict__ h1, const float* __restrict__ b1,
    bf16* __restrict__ out1b,
    const float* __restrict__ Vs, const float* __restrict__ Vd,
    float* __restrict__ asv2, float* __restrict__ adv2, int N)
{
    int d = blockIdx.x * 8 + (threadIdx.x >> 5);
    if (d >= N) return;
    int ln = threadIdx.x & 31;
    int beg = row_ptr[d], end = row_ptr[d + 1];
    float4 advd = *(const float4*)&adv[d * 4];
    float mx = -1e30f, my = -1e30f, mz = -1e30f, mw = -1e30f;
    float dnx = 0.f, dny = 0.f, dnz = 0.f, dnw = 0.f;
    int hh = ln >> 3;             // my head (channels 4*ln .. all in head ln>>3)
    int c0 = ln * 4;
    float a0 = 0.f, a1 = 0.f, a2 = 0.f, a3 = 0.f;
    for (int j0 = beg; j0 < end; j0 += 32) {
        int jj = j0 + ln;
        bool valid = jj < end;
        int s_e = valid ? sidx[jj] : 0;
        float lx = -1e30f, ly = -1e30f, lz = -1e30f, lw = -1e30f;
        if (valid) {
            float4 av = *(const float4*)&asv[s_e * 4];
            lx = av.x + advd.x; lx = lx > 0.f ? lx : 0.2f * lx;
            ly = av.y + advd.y; ly = ly > 0.f ? ly : 0.2f * ly;
            lz = av.z + advd.z; lz = lz > 0.f ? lz : 0.2f * lz;
            lw = av.w + advd.w; lw = lw > 0.f ? lw : 0.2f * lw;
        }
        float cx = lx, cy = ly, cz = lz, cw = lw;
#pragma unroll
        for (int off = 16; off; off >>= 1) {
            cx = fmaxf(cx, __shfl_xor(cx, off, 32));
            cy = fmaxf(cy, __shfl_xor(cy, off, 32));
            cz = fmaxf(cz, __shfl_xor(cz, off, 32));
            cw = fmaxf(cw, __shfl_xor(cw, off, 32));
        }
        float nx = fmaxf(mx, cx), ny = fmaxf(my, cy);
        float nz = fmaxf(mz, cz), nw = fmaxf(mw, cw);
        float rx = __expf(mx - nx), ry = __expf(my - ny);
        float rz = __expf(mz - nz), rw = __expf(mw - nw);
        mx = nx; my = ny; mz = nz; mw = nw;
        float wx = valid ? __expf(lx - nx) : 0.f;
        float wy = valid ? __expf(ly - ny) : 0.f;
        float wz = valid ? __expf(lz - nz) : 0.f;
        float ww = valid ? __expf(lw - nw) : 0.f;
        float sx = wx, sy = wy, sz = wz, sw = ww;
#pragma unroll
        for (int off = 16; off; off >>= 1) {
            sx += __shfl_xor(sx, off, 32);
            sy += __shfl_xor(sy, off, 32);
            sz += __shfl_xor(sz, off, 32);
            sw += __shfl_xor(sw, off, 32);
        }
        dnx = dnx * rx + sx; dny = dny * ry + sy;
        dnz = dnz * rz + sz; dnw = dnw * rw + sw;
        float rh = hh == 0 ? rx : hh == 1 ? ry : hh == 2 ? rz : rw;
        a0 *= rh; a1 *= rh; a2 *= rh; a3 *= rh;
        int cnt = min(32, end - j0);
        for (int k = 0; k < cnt; ++k) {
            int sk = __shfl(s_e, k, 32);
            float bx = __shfl(wx, k, 32);
            float by = __shfl(wy, k, 32);
            float bz = __shfl(wz, k, 32);
            float bw = __shfl(ww, k, 32);
            float wk = hh == 0 ? bx : hh == 1 ? by : hh == 2 ? bz : bw;
            u32x2 u = *(const u32x2*)((const u16*)h1 + (long)sk * 128 + c0);
            a0 += wk * bflo(u.x); a1 += wk * bfhi(u.x);
            a2 += wk * bflo(u.y); a3 += wk * bfhi(u.y);
        }
    }
    float dh = hh == 0 ? dnx : hh == 1 ? dny : hh == 2 ? dnz : dnw;
    float inv = 1.f / (dh + 1e-16f);
    float4 bv = *(const float4*)&b1[c0];
    float v0 = a0 * inv + bv.x;
    float v1 = a1 * inv + bv.y;
    float v2 = a2 * inv + bv.z;
    float v3 = a3 * inv + bv.w;
    v0 = v0 > 0.f ? v0 : (__expf(v0) - 1.f);
    v1 = v1 > 0.f ? v1 : (__expf(v1) - 1.f);
    v2 = v2 > 0.f ? v2 : (__expf(v2) - 1.f);
    v3 = v3 > 0.f ? v3 : (__expf(v3) - 1.f);
    u16 q0 = f2bf(v0), q1 = f2bf(v1), q2 = f2bf(v2), q3 = f2bf(v3);
    u32x2 pv;
    pv.x = (u32)q0 | ((u32)q1 << 16);
    pv.y = (u32)q2 | ((u32)q3 << 16);
    *(u32x2*)((u16*)out1b + (long)d * 128 + c0) = pv;
    // fused layer-2 logits from the bf16-rounded row (matches old alpha2v)
    float f0 = bf2f(q0), f1 = bf2f(q1), f2 = bf2f(q2), f3 = bf2f(q3);
#pragma unroll
    for (int h = 0; h < 4; ++h) {
        float4 vs = *(const float4*)&Vs[h * 128 + c0];
        float4 vd = *(const float4*)&Vd[h * 128 + c0];
        float s = f0 * vs.x + f1 * vs.y + f2 * vs.z + f3 * vs.w;
        float t2 = f0 * vd.x + f1 * vd.y + f2 * vd.z + f3 * vd.w;
#pragma unroll
        for (int off = 16; off; off >>= 1) {
            s += __shfl_xor(s, off, 32);
            t2 += __shfl_xor(t2, off, 32);
        }
        if (ln == 0) { asv2[d * 4 + h] = s; adv2[d * 4 + h] = t2; }
    }
}

// ---- layer-2 FUSED: online-softmax + 4-head gather -> Z[N,512] bf16 -----
// Same group structure; 16 accumulators (4 heads x 4 ch). Z stores are
// nontemporal to protect out1b's cache residency during the gather.
__global__ __launch_bounds__(256) void agg2f_k(
    const int* __restrict__ row_ptr, const int* __restrict__ sidx,
    const float* __restrict__ asv, const float* __restrict__ adv,
    const bf16* __restrict__ out1b, u16* __restrict__ Z, int N)
{
    int d = blockIdx.x * 8 + (threadIdx.x >> 5);
    if (d >= N) return;
    int ln = threadIdx.x & 31;
    int c0 = ln * 4;
    int beg = row_ptr[d], end = row_ptr[d + 1];
    float4 advd = *(const float4*)&adv[d * 4];
    float mx = -1e30f, my = -1e30f, mz = -1e30f, mw = -1e30f;
    float dnx = 0.f, dny = 0.f, dnz = 0.f, dnw = 0.f;
    float h0c0 = 0.f, h0c1 = 0.f, h0c2 = 0.f, h0c3 = 0.f;
    float h1c0 = 0.f, h1c1 = 0.f, h1c2 = 0.f, h1c3 = 0.f;
    float h2c0 = 0.f, h2c1 = 0.f, h2c2 = 0.f, h2c3 = 0.f;
    float h3c0 = 0.f, h3c1 = 0.f, h3c2 = 0.f, h3c3 = 0.f;
    for (int j0 = beg; j0 < end; j0 += 32) {
        int jj = j0 + ln;
        bool valid = jj < end;
        int s_e = valid ? sidx[jj] : 0;
        float lx = -1e30f, ly = -1e30f, lz = -1e30f, lw = -1e30f;
        if (valid) {
            float4 av = *(const float4*)&asv[s_e * 4];
            lx = av.x + advd.x; lx = lx > 0.f ? lx : 0.2f * lx;
            ly = av.y + advd.y; ly = ly > 0.f ? ly : 0.2f * ly;
            lz = av.z + advd.z; lz = lz > 0.f ? lz : 0.2f * lz;
            lw = av.w + advd.w; lw = lw > 0.f ? lw : 0.2f * lw;
        }
        float cx = lx, cy = ly, cz = lz, cw = lw;
#pragma unroll
        for (int off = 16; off; off >>= 1) {
            cx = fmaxf(cx, __shfl_xor(cx, off, 32));
            cy = fmaxf(cy, __shfl_xor(cy, off, 32));
            cz = fmaxf(cz, __shfl_xor(cz, off, 32));
            cw = fmaxf(cw, __shfl_xor(cw, off, 32));
        }
        float nx = fmaxf(mx, cx), ny = fmaxf(my, cy);
        float nz = fmaxf(mz, cz), nw = fmaxf(mw, cw);
        float rx = __expf(mx - nx), ry = __expf(my - ny);
        float rz = __expf(mz - nz), rw = __expf(mw - nw);
        mx = nx; my = ny; mz = nz; mw = nw;
        float wx = valid ? __expf(lx - nx) : 0.f;
        float wy = valid ? __expf(ly - ny) : 0.f;
        float wz = valid ? __expf(lz - nz) : 0.f;
        float ww = valid ? __expf(lw - nw) : 0.f;
        float sx = wx, sy = wy, sz = wz, sw = ww;
#pragma unroll
        for (int off = 16; off; off >>= 1) {
            sx += __shfl_xor(sx, off, 32);
            sy += __shfl_xor(sy, off, 32);
            sz += __shfl_xor(sz, off, 32);
            sw += __shfl_xor(sw, off, 32);
        }
        dnx = dnx * rx + sx; dny = dny * ry + sy;
        dnz = dnz * rz + sz; dnw = dnw * rw + sw;
        h0c0 *= rx; h0c1 *= rx; h0c2 *= rx; h0c3 *= rx;
        h1c0 *= ry; h1c1 *= ry; h1c2 *= ry; h1c3 *= ry;
        h2c0 *= rz; h2c1 *= rz; h2c2 *= rz; h2c3 *= rz;
        h3c0 *= rw; h3c1 *= rw; h3c2 *= rw; h3c3 *= rw;
        int cnt = min(32, end - j0);
        for (int k = 0; k < cnt; ++k) {
            int sk = __shfl(s_e, k, 32);
            float bx = __shfl(wx, k, 32);
            float by = __shfl(wy, k, 32);
            float bz = __shfl(wz, k, 32);
            float bw = __shfl(ww, k, 32);
            u32x2 u = *(const u32x2*)((const u16*)out1b + (long)sk * 128 + c0);
            float e0 = bflo(u.x), e1 = bfhi(u.x), e2 = bflo(u.y), e3 = bfhi(u.y);
            h0c0 += bx * e0; h0c1 += bx * e1; h0c2 += bx * e2; h0c3 += bx * e3;
            h1c0 += by * e0; h1c1 += by * e1; h1c2 += by * e2; h1c3 += by * e3;
            h2c0 += bz * e0; h2c1 += bz * e1; h2c2 += bz * e2; h2c3 += bz * e3;
            h3c0 += bw * e0; h3c1 += bw * e1; h3c2 += bw * e2; h3c3 += bw * e3;
        }
    }
    float ix = 0.25f / (dnx + 1e-16f);
    float iy = 0.25f / (dny + 1e-16f);
    float iz = 0.25f / (dnz + 1e-16f);
    float iw = 0.25f / (dnw + 1e-16f);
    u16* zrow = Z + (long)d * 512 + c0;
    u32x2 p0, p1, p2, p3;
    p0.x = (u32)f2bf(h0c0 * ix) | ((u32)f2bf(h0c1 * ix) << 16);
    p0.y = (u32)f2bf(h0c2 * ix) | ((u32)f2bf(h0c3 * ix) << 16);
    p1.x = (u32)f2bf(h1c0 * iy) | ((u32)f2bf(h1c1 * iy) << 16);
    p1.y = (u32)f2bf(h1c2 * iy) | ((u32)f2bf(h1c3 * iy) << 16);
    p2.x = (u32)f2bf(h2c0 * iz) | ((u32)f2bf(h2c1 * iz) << 16);
    p2.y = (u32)f2bf(h2c2 * iz) | ((u32)f2bf(h2c3 * iz) << 16);
    p3.x = (u32)f2bf(h3c0 * iw) | ((u32)f2bf(h3c1 * iw) << 16);
    p3.y = (u32)f2bf(h3c2 * iw) | ((u32)f2bf(h3c3 * iw) << 16);
    __builtin_nontemporal_store(p0, (u32x2*)(zrow));
    __builtin_nontemporal_store(p1, (u32x2*)(zrow + 128));
    __builtin_nontemporal_store(p2, (u32x2*)(zrow + 256));
    __builtin_nontemporal_store(p3, (u32x2*)(zrow + 384));
}

// ---- final linear: out[N,64] = emb[N,128] @ W_lin + b -------------------
__global__ __launch_bounds__(256) void final_k(const float* __restrict__ emb,
                                               const float* __restrict__ W,
                                               const float* __restrict__ bias,
                                               float* __restrict__ out, int N)
{
    __shared__ float Ws[128 * 64];
    __shared__ float Es[4][132];
    const int tid = threadIdx.x;
    for (int i = tid; i < 128 * 64; i += 256) Ws[i] = W[i];
    int node0 = blockIdx.x * 4;
    for (int i = tid; i < 512; i += 256) {
        int nn = i >> 7, c = i & 127;
        int n = node0 + nn;
        Es[nn][c] = (n < N) ? emb[(long)n * 128 + c] : 0.f;
    }
    __syncthreads();
    int nn = tid >> 6, j = tid & 63;
    int n = node0 + nn;
    if (n >= N) return;
    float acc = bias[j];
#pragma unroll 8
    for (int k = 0; k < 128; ++k) acc += Es[nn][k] * Ws[k * 64 + j];
    __builtin_nontemporal_store(acc, &out[(long)n * 64 + j]);
}

// ---- diagnostic ---------------------------------------------------------
__global__ void diag_k(float* __restrict__ out, long n, float val)
{
    long i = (long)blockIdx.x * blockDim.x + threadIdx.x;
    if (i >= n) return;
    out[i] = val;
}

extern "C" void kernel_launch(void* const* d_in, const int* in_sizes, int n_in,
                              void* d_out, int out_size, void* d_ws, size_t ws_size,
                              hipStream_t stream)
{
    const float* x   = (const float*)d_in[0];
    const int* ei    = (const int*)d_in[1];
    const float* W1  = (const float*)d_in[2];
    const float* as1 = (const float*)d_in[3];
    const float* ad1 = (const float*)d_in[4];
    const float* b1  = (const float*)d_in[5];
    const float* W2  = (const float*)d_in[6];
    const float* as2 = (const float*)d_in[7];
    const float* ad2 = (const float*)d_in[8];
    const float* b2  = (const float*)d_in[9];
    const float* Wl  = (const float*)d_in[10];
    const float* bl  = (const float*)d_in[11];

    const int N = in_sizes[0] / 512;
    const int E = in_sizes[1] / 2;
    const int Etot = E + N;
    const int* src = ei;
    const int* dst = ei + E;

    float* outp = (float*)d_out;          // [N,64]
    float* embp = outp + (size_t)N * 64;  // [N,128] f32
    // out1b (bf16 [N,128]) parked in embp region (dead before gemm2 writes emb)
    bf16* out1b = (bf16*)embp;

    // ---- workspace layout (~113 MB; known-safe floor = 119.6 MB) ----
    char* wsb = (char*)d_ws;
    u16*   Z     = (u16*)wsb;                               // N*512 bf16 (layer-2 aggregate)
    bf16*  h1    = (bf16*)wsb;                              // N*128 bf16 (alias; dead before Z written)
    float* asv   = (float*)(wsb + (size_t)N * 512 * sizeof(u16));   // N*4 (layer1 src logits)
    float* adv   = asv + (size_t)N * 4;                     // N*4
    float* asv2  = adv + (size_t)N * 4;                     // N*4 (layer2 src logits)
    float* adv2  = asv2 + (size_t)N * 4;                    // N*4
    int*   cnt   = (int*)(adv2 + (size_t)N * 4);            // N
    int*   row_ptr = cnt + N;                               // N+1
    int*   wofs  = row_ptr + (N + 1);                       // N
    int*   bsum  = wofs + N;                                // 512
    int*   bofs  = bsum + 512;                              // 512
    int*   sidx  = bofs + 512;                              // Etot (resolved src)
    char*  pw    = (char*)(sidx + Etot);
    pw = (char*)(((uintptr_t)pw + 255) & ~(uintptr_t)255);
    u16*   w1t_hi = (u16*)pw;                               // [128][512]
    u16*   w1t_lo = w1t_hi + 128 * 512;
    u16*   w2t_hi = w1t_lo + 128 * 512;                     // [128][512] permuted W2
    u16*   w2t_lo = w2t_hi + 512 * 128;
    float* Vs    = (float*)(w2t_lo + 512 * 128);            // 512
    float* Vd    = Vs + 512;                                // 512
    size_t need  = (size_t)((char*)(Vd + 512) - wsb);

    dim3 blk(256);
    long n_out_total = (long)N * 192;

    if (ws_size < need) {
        float val = 100.0f + (float)(ws_size >> 20);
        diag_k<<<(int)((n_out_total + 255) / 256), blk, 0, stream>>>(outp, n_out_total, val);
        return;
    }

    const int B = (N + 255) / 256;  // scan blocks (<=512 for N<=131072)
    const int gM = (N + 127) / 128; // MFMA gemm row-blocks
    const int gAgg = (N + 7) / 8;   // fused agg blocks (8 nodes / 256 threads)

    // ---- weight prep (tiny, independent of everything) ----
    tsplit_k<<<(512 * 128 + 255) / 256, blk, 0, stream>>>(W1, 512, 128, w1t_hi, w1t_lo);
    tsplit2_k<<<(128 * 512 + 255) / 256, blk, 0, stream>>>(W2, w2t_hi, w2t_lo);
    vmat_k<<<2, blk, 0, stream>>>(W2, as2, ad2, Vs, Vd);

    // ---- CSR build (by dst) ----
    init_cnt_k<<<B, blk, 0, stream>>>(cnt, N);
    hist_k<<<(E + 255) / 256, blk, 0, stream>>>(dst, E, cnt);
    scan_blk_k<<<B, blk, 0, stream>>>(cnt, row_ptr, bsum, N);
    scan_top_k<<<1, 512, 0, stream>>>(bsum, bofs, B);
    add_off_k<<<B, blk, 0, stream>>>(row_ptr, bofs, wofs, N, Etot);
    scatter_k<<<(Etot + 255) / 256, blk, 0, stream>>>(dst, src, E, Etot, wofs, sidx);

    // ---- layer 1: h1 = x @ W1 (split-precision MFMA) ----
    gemm_mfma<true, u16><<<dim3(1, gM), blk, 0, stream>>>(
        (const void*)x, w1t_hi, w1t_lo, (u16*)h1, N, 128, 512, nullptr);
    alpha4_k<<<(N * 4 + 255) / 256, blk, 0, stream>>>(h1, as1, ad1, asv, adv, N);
    // fused: softmax + gather + bias + ELU + layer-2 logits
    agg1f_k<<<gAgg, blk, 0, stream>>>(row_ptr, sidx, asv, adv, h1, b1, out1b,
                                      Vs, Vd, asv2, adv2, N);

    // ---- layer 2 (h2 never materialized) ----
    agg2f_k<<<gAgg, blk, 0, stream>>>(row_ptr, sidx, asv2, adv2, out1b, Z, N);
    gemm_mfma<false, float><<<dim3(1, gM), blk, 0, stream>>>(
        (const void*)Z, w2t_hi, w2t_lo, embp, N, 128, 512, b2);

    // ---- head ----
    final_k<<<(N + 3) / 4, blk, 0, stream>>>(embp, Wl, bl, outp, N);
}